// Round 3
// baseline (421.768 us; speedup 1.0000x reference)
//
#include <hip/hip_runtime.h>
#include <cstddef>

// Problem constants
#define NB   4
#define CIN  256
#define TT   16
#define HH   28
#define WW   28
#define LL   (TT*HH*WW)      // 12544 = 49*256
#define MIDC 32
#define KCC  128
#define VCC  256
#define HC   8
#define HK   16
#define HV   32
#define CTXSPLIT 49
#define CTXSTR 544           // 16*32 + 16 sum column
#define EPSV 1e-5f

struct Quad  { const float* p[4]; };
struct Pw1A  { const float* wt[3]; const float* b[3]; float* out[3]; };
struct DwA   { const float* in[3]; const float* w[3]; const float* b[3]; float* out[3]; };
struct Pw2A  { const float* in[3]; const float* w[3]; const float* b[3]; float* out[3]; int ocn[3]; };

// ------- transpose pw1 weights [32][256] -> [256][32] for scalar loads ------
__global__ __launch_bounds__(256) void transpose_w(Quad w, float* __restrict__ wt)
{
    const int idx = blockIdx.x*256 + threadIdx.x;    // 4 * 8192
    const int set = idx >> 13, rem = idx & 8191;
    const int m = rem >> 8, c = rem & 255;
    wt[set*8192 + c*MIDC + m] = w.p[set][rem];
}

// ---------------- pw1: [32x256] @ [256xL] + b, scalar-load weights ----------
// wt is [256][32] (c-major). grid (98, NB, nsets), block 128.
__global__ __launch_bounds__(128) void pw1_s(
    const float* __restrict__ in, Pw1A a)
{
    const int z = blockIdx.z;
    const float* __restrict__ wt = a.wt[z];
    const float* __restrict__ bi = a.b[z];
    const int n = blockIdx.y;
    const int l = blockIdx.x*128 + threadIdx.x;

    float acc[MIDC];
#pragma unroll
    for (int m = 0; m < MIDC; ++m) acc[m] = 0.f;

    const float* ip = in + (size_t)n*CIN*LL + l;
#pragma unroll 2
    for (int c = 0; c < CIN; ++c) {
        const float x = ip[(size_t)c*LL];
        const float* __restrict__ wc = wt + c*MIDC;   // uniform -> s_load
#pragma unroll
        for (int m = 0; m < MIDC; ++m) acc[m] += wc[m] * x;
    }
    float* op = a.out[z] + (size_t)n*MIDC*LL + l;
#pragma unroll
    for (int m = 0; m < MIDC; ++m) op[(size_t)m*LL] = acc[m] + bi[m];
}

// ---------------- depthwise 3x3x3, pad 1, z selects set ---------------------
__global__ __launch_bounds__(256) void dw_fused(DwA a)
{
    const int z  = blockIdx.z;
    const int nm = blockIdx.y;             // n*32 + m
    const int m  = nm & (MIDC-1);
    const int tz = blockIdx.x;             // t
    __shared__ float wl[27];
    if (threadIdx.x < 27) wl[threadIdx.x] = a.w[z][m*27 + threadIdx.x];
    __syncthreads();
    const float bias = a.b[z][m];
    const float* ip = a.in[z] + (size_t)nm*LL;
    float* op = a.out[z] + (size_t)nm*LL + tz*HH*WW;

    for (int hw = threadIdx.x; hw < HH*WW; hw += 256) {
        const int y = hw / WW, x = hw - y*WW;
        float acc = bias;
#pragma unroll
        for (int dz = 0; dz < 3; ++dz) {
            const int zz = tz + dz - 1;
            if (zz < 0 || zz >= TT) continue;
#pragma unroll
            for (int dy = 0; dy < 3; ++dy) {
                const int yy = y + dy - 1;
                if (yy < 0 || yy >= HH) continue;
#pragma unroll
                for (int dx = 0; dx < 3; ++dx) {
                    const int xx = x + dx - 1;
                    if (xx < 0 || xx >= WW) continue;
                    acc += wl[(dz*3+dy)*3+dx] * ip[((size_t)zz*HH + yy)*WW + xx];
                }
            }
        }
        op[hw] = acc;
    }
}

// ---------------- pw2 (k,q,v), scalar-load weights, 64-chan chunks ----------
__global__ __launch_bounds__(256) void pw2_fused(Pw2A a)
{
    const int z = blockIdx.z;
    int set, oz;
    if (z < 2)      { set = 0; oz = z; }
    else if (z < 4) { set = 1; oz = z - 2; }
    else            { set = 2; oz = z - 4; }

    const float* __restrict__ wz = a.w[set] + (size_t)oz*64*MIDC;  // [64][32]
    const float* __restrict__ bz = a.b[set] + oz*64;
    const int n = blockIdx.y;
    const int l = blockIdx.x*256 + threadIdx.x;
    float r[MIDC];
    const float* ip = a.in[set] + (size_t)n*MIDC*LL + l;
#pragma unroll
    for (int m = 0; m < MIDC; ++m) r[m] = ip[(size_t)m*LL];

    const int OC = a.ocn[set];
    float* op = a.out[set] + ((size_t)n*OC + oz*64)*LL + l;
#pragma unroll 2
    for (int o = 0; o < 64; ++o) {
        const float* __restrict__ wo = wz + o*MIDC;   // uniform -> s_load
        float acc = bz[o];
#pragma unroll
        for (int m = 0; m < MIDC; ++m) acc += wo[m] * r[m];
        op[(size_t)o*LL] = acc;
    }
}

// ------- context partials + per-row sum of exp(K), no max-sub needed --------
// K values are O(0.01): exp without max subtraction is exact-safe in fp32.
__global__ __launch_bounds__(256) void ctx_partial(
    const float* __restrict__ Kb, const float* __restrict__ Vb,
    float* __restrict__ ctxp)
{
    const int nh = blockIdx.y;                 // 32
    const int sp = blockIdx.x;                 // 49
    const int n = nh >> 3, h = nh & 7;
    __shared__ float Kt[HK][260];
    __shared__ float Vt[HV][260];
    const int t = threadIdx.x;
    const int l0 = sp*256;
    const float* Kp = Kb + ((size_t)(n*KCC + h*HK))*LL + l0;
    const float* Vp = Vb + ((size_t)(n*VCC + h*HV))*LL + l0;
#pragma unroll
    for (int m = 0; m < HK; ++m) Kt[m][t] = __expf(Kp[(size_t)m*LL + t]);
#pragma unroll
    for (int m = 0; m < HV; ++m) Vt[m][t] = Vp[(size_t)m*LL + t];
    __syncthreads();

    const int kk = t >> 4, v0 = t & 15;
    float acc0 = 0.f, acc1 = 0.f, asum = 0.f;
#pragma unroll 2
    for (int j = 0; j < 256; j += 4) {
        float4 kv = *reinterpret_cast<const float4*>(&Kt[kk][j]);
        float4 va = *reinterpret_cast<const float4*>(&Vt[v0][j]);
        float4 vb = *reinterpret_cast<const float4*>(&Vt[v0+16][j]);
        acc0 += kv.x*va.x; acc0 += kv.y*va.y; acc0 += kv.z*va.z; acc0 += kv.w*va.w;
        acc1 += kv.x*vb.x; acc1 += kv.y*vb.y; acc1 += kv.z*vb.z; acc1 += kv.w*vb.w;
        asum += kv.x + kv.y + kv.z + kv.w;
    }
    float* cp = ctxp + ((size_t)nh*CTXSPLIT + sp)*CTXSTR;
    cp[kk*HV + v0]      = acc0;
    cp[kk*HV + v0 + 16] = acc1;
    if (v0 == 0) cp[512 + kk] = asum;
}

// ------- reduce partials and normalize by per-row sum ------------------------
__global__ void ctx_reduce(const float* __restrict__ ctxp, float* __restrict__ ctx)
{
    const int idx = blockIdx.x*256 + threadIdx.x;   // 16384
    const int nh = idx >> 9;
    const int p  = idx & 511;
    const int k  = p >> 5;
    float s = 0.f, se = 0.f;
    for (int sp = 0; sp < CTXSPLIT; ++sp) {
        const float* cp = ctxp + ((size_t)nh*CTXSPLIT + sp)*CTXSTR;
        s  += cp[p];
        se += cp[512 + k];
    }
    ctx[idx] = s / se;
}

// ------- attended with fused Q channel-softmax; ctx via scalar loads --------
__global__ __launch_bounds__(256) void attended_kernel(
    const float* __restrict__ ctx, const float* __restrict__ Qb,
    float* __restrict__ agg)
{
    const int nh = blockIdx.y;
    const int n = nh >> 3, h = nh & 7;
    const int l = blockIdx.x*256 + threadIdx.x;
    const float* __restrict__ cl = ctx + (size_t)nh*512;   // uniform -> s_load

    const float* Qp = Qb + ((size_t)(n*KCC + h*HK))*LL + l;
    float q[HK];
    float mx = -1e30f;
#pragma unroll
    for (int k = 0; k < HK; ++k) { q[k] = Qp[(size_t)k*LL]; mx = fmaxf(mx, q[k]); }
    float s = 0.f;
#pragma unroll
    for (int k = 0; k < HK; ++k) { q[k] = __expf(q[k] - mx); s += q[k]; }
    const float inv = 1.f / s;
#pragma unroll
    for (int k = 0; k < HK; ++k) q[k] *= inv;

    float* ap = agg + ((size_t)(n*VCC + h*HV))*LL + l;
#pragma unroll 4
    for (int v = 0; v < HV; ++v) {
        float acc = 0.f;
#pragma unroll
        for (int k = 0; k < HK; ++k) acc += q[k] * cl[k*HV + v];
        ap[(size_t)v*LL] = acc;
    }
}

// ------- pw2 of reproj + residual + global-LN partials, scalar weights ------
__global__ __launch_bounds__(256) void pw2r_kernel(
    const float* __restrict__ in,    // dwr [N][32][L]
    const float* __restrict__ w,     // [256][32]
    const float* __restrict__ b,     // [256]
    const float* __restrict__ resid, // input_ [N][256][L]
    float* __restrict__ xout,        // [N][256][L]
    float* __restrict__ part)        // [2 * 784]
{
    const int oz = blockIdx.z;       // 0..3
    __shared__ float red[256];
    const int t = threadIdx.x;
    const float* __restrict__ wz = w + (size_t)oz*64*MIDC;
    const float* __restrict__ bz = b + oz*64;

    const int n = blockIdx.y;
    const int l = blockIdx.x*256 + t;
    float r[MIDC];
    const float* ip = in + (size_t)n*MIDC*LL + l;
#pragma unroll
    for (int m = 0; m < MIDC; ++m) r[m] = ip[(size_t)m*LL];

    const float* rp = resid + ((size_t)n*CIN + oz*64)*LL + l;
    float* xp = xout + ((size_t)n*CIN + oz*64)*LL + l;
    float s1 = 0.f, s2 = 0.f;
#pragma unroll 2
    for (int o = 0; o < 64; ++o) {
        const float* __restrict__ wo = wz + o*MIDC;   // uniform -> s_load
        float acc = bz[o];
#pragma unroll
        for (int m = 0; m < MIDC; ++m) acc += wo[m] * r[m];
        acc += rp[(size_t)o*LL];
        xp[(size_t)o*LL] = acc;
        s1 += acc; s2 += acc*acc;
    }
    const int bid = (blockIdx.y*gridDim.x + blockIdx.x)*4 + oz;   // 0..783
    red[t] = s1; __syncthreads();
    for (int s = 128; s > 0; s >>= 1) { if (t < s) red[t] += red[t+s]; __syncthreads(); }
    if (t == 0) part[2*bid] = red[0];
    __syncthreads();
    red[t] = s2; __syncthreads();
    for (int s = 128; s > 0; s >>= 1) { if (t < s) red[t] += red[t+s]; __syncthreads(); }
    if (t == 0) part[2*bid + 1] = red[0];
}

__global__ void stats_kernel(const float* __restrict__ part, int nblocks,
                             float* __restrict__ stats)
{
    __shared__ float r1[256], r2[256];
    const int t = threadIdx.x;
    float s1 = 0.f, s2 = 0.f;
    for (int i = t; i < nblocks; i += 256) { s1 += part[2*i]; s2 += part[2*i+1]; }
    r1[t] = s1; r2[t] = s2; __syncthreads();
    for (int s = 128; s > 0; s >>= 1) { if (t < s) { r1[t] += r1[t+s]; r2[t] += r2[t+s]; } __syncthreads(); }
    if (t == 0) {
        const float M = (float)NB*CIN*LL;
        const float mu = r1[0]/M;
        const float var = r2[0]/M - mu*mu;
        stats[0] = mu;
        stats[1] = 1.0f/sqrtf(var + EPSV);
    }
}

__global__ __launch_bounds__(256) void norm_kernel(
    const float* __restrict__ x, const float* __restrict__ stats,
    float* __restrict__ out)
{
    const float mu = stats[0], inv = stats[1];
    const size_t total = (size_t)NB*CIN*LL;   // divisible by 4
    for (size_t i = ((size_t)blockIdx.x*256 + threadIdx.x)*4; i < total;
         i += (size_t)gridDim.x*256*4) {
        float4 v = *reinterpret_cast<const float4*>(x + i);
        float4 o;
        o.x = (v.x-mu)*inv; o.y = (v.y-mu)*inv; o.z = (v.z-mu)*inv; o.w = (v.w-mu)*inv;
        *reinterpret_cast<float4*>(out + i) = o;
    }
}

// ------------------------------- launcher ------------------------------------
extern "C" void kernel_launch(void* const* d_in, const int* in_sizes, int n_in,
                              void* d_out, int out_size, void* d_ws, size_t ws_size,
                              hipStream_t stream) {
    const float* input   = (const float*)d_in[0];
    const float* k_pw1_w = (const float*)d_in[1];
    const float* k_pw1_b = (const float*)d_in[2];
    const float* k_dw_w  = (const float*)d_in[3];
    const float* k_dw_b  = (const float*)d_in[4];
    const float* k_pw2_w = (const float*)d_in[5];
    const float* k_pw2_b = (const float*)d_in[6];
    const float* q_pw1_w = (const float*)d_in[7];
    const float* q_pw1_b = (const float*)d_in[8];
    const float* q_dw_w  = (const float*)d_in[9];
    const float* q_dw_b  = (const float*)d_in[10];
    const float* q_pw2_w = (const float*)d_in[11];
    const float* q_pw2_b = (const float*)d_in[12];
    const float* v_pw1_w = (const float*)d_in[13];
    const float* v_pw1_b = (const float*)d_in[14];
    const float* v_dw_w  = (const float*)d_in[15];
    const float* v_dw_b  = (const float*)d_in[16];
    const float* v_pw2_w = (const float*)d_in[17];
    const float* v_pw2_b = (const float*)d_in[18];
    const float* r_pw1_w = (const float*)d_in[19];
    const float* r_pw1_b = (const float*)d_in[20];
    const float* r_dw_w  = (const float*)d_in[21];
    const float* r_dw_b  = (const float*)d_in[22];
    const float* r_pw2_w = (const float*)d_in[23];
    const float* r_pw2_b = (const float*)d_in[24];

    float* ws = (float*)d_ws;
    const size_t N32L = (size_t)NB*MIDC*LL;     // 1,605,632
    const size_t NKL  = (size_t)NB*KCC*LL;      // 6,422,528
    const size_t NVL  = (size_t)NB*VCC*LL;      // 12,845,056

    float* midk = ws;
    float* midq = midk + N32L;
    float* midv = midq + N32L;
    float* dk   = ws + 3*N32L;
    float* dq   = dk + N32L;
    float* dv   = dq + N32L;
    float* Kb   = ws + 6*N32L;
    float* Qb   = Kb + NKL;
    float* Vb   = Qb + NKL;
    float* agg  = Vb;          // V dead after ctx_partial
    float* xb   = Kb;          // K,Q dead after attended; spans exactly NVL
    // regions reused after their producers are consumed:
    float* ctxp = dk;          // 32*49*544 = 852,992 <= N32L; dk dead after pw2_fused
    float* ctx  = dv;          // 16,384 floats; dv dead after pw2_fused
    float* part = dv + 20000;
    float* statsp = dv + 24000;
    float* midr = midk;        // mids dead after dw_fused
    float* dwr  = dk;          // ctxp dead after ctx_reduce
    // transposed pw1 weights live in d_out (fully overwritten by norm_kernel)
    float* wt   = (float*)d_out;   // 4 * 8192 floats

    // weight transpose for scalar-load pw1
    {
        Quad w = {{k_pw1_w, q_pw1_w, v_pw1_w, r_pw1_w}};
        transpose_w<<<128, 256, 0, stream>>>(w, wt);
    }

    // k/q/v projections
    {
        Pw1A a;
        a.wt[0]=wt; a.wt[1]=wt+8192; a.wt[2]=wt+16384;
        a.b[0]=k_pw1_b; a.b[1]=q_pw1_b; a.b[2]=v_pw1_b;
        a.out[0]=midk; a.out[1]=midq; a.out[2]=midv;
        pw1_s<<<dim3(98, NB, 3), 128, 0, stream>>>(input, a);
    }
    {
        DwA a;
        a.in[0]=midk; a.in[1]=midq; a.in[2]=midv;
        a.w[0]=k_dw_w; a.w[1]=q_dw_w; a.w[2]=v_dw_w;
        a.b[0]=k_dw_b; a.b[1]=q_dw_b; a.b[2]=v_dw_b;
        a.out[0]=dk; a.out[1]=dq; a.out[2]=dv;
        dw_fused<<<dim3(TT, NB*MIDC, 3), 256, 0, stream>>>(a);
    }
    {
        Pw2A a;
        a.in[0]=dk; a.in[1]=dq; a.in[2]=dv;
        a.w[0]=k_pw2_w; a.w[1]=q_pw2_w; a.w[2]=v_pw2_w;
        a.b[0]=k_pw2_b; a.b[1]=q_pw2_b; a.b[2]=v_pw2_b;
        a.out[0]=Kb; a.out[1]=Qb; a.out[2]=Vb;
        a.ocn[0]=KCC; a.ocn[1]=KCC; a.ocn[2]=VCC;
        pw2_fused<<<dim3(49, NB, 8), 256, 0, stream>>>(a);
    }

    // attention
    ctx_partial<<<dim3(CTXSPLIT, NB*HC), 256, 0, stream>>>(Kb, Vb, ctxp);
    ctx_reduce<<<64, 256, 0, stream>>>(ctxp, ctx);
    attended_kernel<<<dim3(49, NB*HC), 256, 0, stream>>>(ctx, Qb, agg);

    // reprojection + residual + global layernorm
    {
        Pw1A a;
        a.wt[0]=wt+24576; a.b[0]=r_pw1_b; a.out[0]=midr;
        a.wt[1]=a.wt[0];  a.b[1]=a.b[0];  a.out[1]=midr;
        a.wt[2]=a.wt[0];  a.b[2]=a.b[0];  a.out[2]=midr;
        pw1_s<<<dim3(98, NB, 1), 128, 0, stream>>>(agg, a);
    }
    {
        DwA a;
        a.in[0]=midr; a.w[0]=r_dw_w; a.b[0]=r_dw_b; a.out[0]=dwr;
        a.in[1]=midr; a.w[1]=r_dw_w; a.b[1]=r_dw_b; a.out[1]=dwr;
        a.in[2]=midr; a.w[2]=r_dw_w; a.b[2]=r_dw_b; a.out[2]=dwr;
        dw_fused<<<dim3(TT, NB*MIDC, 1), 256, 0, stream>>>(a);
    }
    pw2r_kernel<<<dim3(49, NB, 4), 256, 0, stream>>>(dwr, r_pw2_w, r_pw2_b, input, xb, part);
    stats_kernel<<<1, 256, 0, stream>>>(part, 4*49*NB, statsp);
    norm_kernel<<<2048, 256, 0, stream>>>(xb, statsp, (float*)d_out);
}

// Round 4
// 388.873 us; speedup vs baseline: 1.0846x; 1.0846x over previous
//
#include <hip/hip_runtime.h>
#include <cstddef>

// Problem constants
#define NB   4
#define CIN  256
#define TT   16
#define HH   28
#define WW   28
#define LL   (TT*HH*WW)      // 12544 = 49*256
#define MIDC 32
#define KCC  128
#define VCC  256
#define HC   8
#define HK   16
#define HV   32
#define CTXSPLIT 49
#define CTXSTR 544           // 16*32 + 16 sum column
#define EPSV 1e-5f

struct Quad  { const float* p[4]; };
struct Pw1A  { const float* wt[3]; const float* b[3]; float* out[3]; };
struct DwA   { const float* in[3]; const float* w[3]; const float* b[3]; float* out[3]; };
struct Pw2A  { const float* in[3]; const float* w[3]; const float* b[3]; float* out[3]; int ocn[3]; };

// ------- transpose pw1 weights [32][256] -> [256][32] once ------------------
__global__ __launch_bounds__(256) void transpose_w(Quad w, float* __restrict__ wt)
{
    const int idx = blockIdx.x*256 + threadIdx.x;    // 4 * 8192
    const int set = idx >> 13, rem = idx & 8191;
    const int m = rem >> 8, c = rem & 255;
    wt[set*8192 + c*MIDC + m] = w.p[set][rem];
}

// ---------------- pw1: [32x256] @ [256xL] + b, LDS weights, 2 l/thread ------
// wt is [256][32] (c-major, pre-transposed). grid (25, NB, nsets), block 256.
__global__ __launch_bounds__(256) void pw1_v2(
    const float* __restrict__ in, Pw1A a)
{
    const int z = blockIdx.z;
    __shared__ float wl[CIN*MIDC];   // 32 KB, [c][m]
    const int t = threadIdx.x;
    {
        const float4* src = reinterpret_cast<const float4*>(a.wt[z]);
        float4* dst = reinterpret_cast<float4*>(wl);
        for (int i = t; i < CIN*MIDC/4; i += 256) dst[i] = src[i];
    }
    __syncthreads();

    const int n = blockIdx.y;
    const int l = blockIdx.x*512 + 2*t;
    if (l >= LL) return;

    float acc0[MIDC], acc1[MIDC];
#pragma unroll
    for (int m = 0; m < MIDC; ++m) { acc0[m] = 0.f; acc1[m] = 0.f; }

    const float* ip = in + (size_t)n*CIN*LL + l;
    for (int c = 0; c < CIN; ++c) {
        float2 x = *reinterpret_cast<const float2*>(ip + (size_t)c*LL);
        const float4* wp = reinterpret_cast<const float4*>(&wl[c*MIDC]);
#pragma unroll
        for (int mq = 0; mq < 8; ++mq) {
            float4 wv = wp[mq];
            acc0[4*mq+0] += wv.x*x.x;  acc1[4*mq+0] += wv.x*x.y;
            acc0[4*mq+1] += wv.y*x.x;  acc1[4*mq+1] += wv.y*x.y;
            acc0[4*mq+2] += wv.z*x.x;  acc1[4*mq+2] += wv.z*x.y;
            acc0[4*mq+3] += wv.w*x.x;  acc1[4*mq+3] += wv.w*x.y;
        }
    }
    const float* __restrict__ bi = a.b[z];
    float* op = a.out[z] + (size_t)n*MIDC*LL + l;
#pragma unroll
    for (int m = 0; m < MIDC; ++m) {
        float2 o2 = { acc0[m] + bi[m], acc1[m] + bi[m] };
        *reinterpret_cast<float2*>(op + (size_t)m*LL) = o2;
    }
}

// ---------------- depthwise 3x3x3, pad 1, z selects set ---------------------
__global__ __launch_bounds__(256) void dw_fused(DwA a)
{
    const int z  = blockIdx.z;
    const int nm = blockIdx.y;             // n*32 + m
    const int m  = nm & (MIDC-1);
    const int tz = blockIdx.x;             // t
    __shared__ float wl[27];
    if (threadIdx.x < 27) wl[threadIdx.x] = a.w[z][m*27 + threadIdx.x];
    __syncthreads();
    const float bias = a.b[z][m];
    const float* ip = a.in[z] + (size_t)nm*LL;
    float* op = a.out[z] + (size_t)nm*LL + tz*HH*WW;

    for (int hw = threadIdx.x; hw < HH*WW; hw += 256) {
        const int y = hw / WW, x = hw - y*WW;
        float acc = bias;
#pragma unroll
        for (int dz = 0; dz < 3; ++dz) {
            const int zz = tz + dz - 1;
            if (zz < 0 || zz >= TT) continue;
#pragma unroll
            for (int dy = 0; dy < 3; ++dy) {
                const int yy = y + dy - 1;
                if (yy < 0 || yy >= HH) continue;
#pragma unroll
                for (int dx = 0; dx < 3; ++dx) {
                    const int xx = x + dx - 1;
                    if (xx < 0 || xx >= WW) continue;
                    acc += wl[(dz*3+dy)*3+dx] * ip[((size_t)zz*HH + yy)*WW + xx];
                }
            }
        }
        op[hw] = acc;
    }
}

// ------- pw2 (k,q,v): LDS weights, 64-chan chunks, 2 l/thread ---------------
__global__ __launch_bounds__(256) void pw2_v2(Pw2A a)
{
    const int z = blockIdx.z;
    int set, oz;
    if (z < 2)      { set = 0; oz = z; }
    else if (z < 4) { set = 1; oz = z - 2; }
    else            { set = 2; oz = z - 4; }

    __shared__ float wl[64*MIDC];   // 8 KB
    const int t = threadIdx.x;
    {
        const float4* src = reinterpret_cast<const float4*>(a.w[set] + (size_t)oz*64*MIDC);
        float4* dst = reinterpret_cast<float4*>(wl);
        for (int i = t; i < 64*MIDC/4; i += 256) dst[i] = src[i];
    }
    __syncthreads();

    const int n = blockIdx.y;
    const int l = blockIdx.x*512 + 2*t;
    if (l >= LL) return;

    float r0[MIDC], r1[MIDC];
    const float* ip = a.in[set] + (size_t)n*MIDC*LL + l;
#pragma unroll
    for (int m = 0; m < MIDC; ++m) {
        float2 x = *reinterpret_cast<const float2*>(ip + (size_t)m*LL);
        r0[m] = x.x; r1[m] = x.y;
    }

    const float* __restrict__ bz = a.b[set] + oz*64;
    const int OC = a.ocn[set];
    float* op = a.out[set] + ((size_t)n*OC + oz*64)*LL + l;
    for (int o = 0; o < 64; ++o) {
        const float4* wp = reinterpret_cast<const float4*>(&wl[o*MIDC]);
        float acc0 = 0.f, acc1 = 0.f;
#pragma unroll
        for (int mq = 0; mq < 8; ++mq) {
            float4 wv = wp[mq];
            acc0 += wv.x*r0[4*mq+0] + wv.y*r0[4*mq+1] + wv.z*r0[4*mq+2] + wv.w*r0[4*mq+3];
            acc1 += wv.x*r1[4*mq+0] + wv.y*r1[4*mq+1] + wv.z*r1[4*mq+2] + wv.w*r1[4*mq+3];
        }
        float2 o2 = { acc0 + bz[o], acc1 + bz[o] };
        *reinterpret_cast<float2*>(op + (size_t)o*LL) = o2;
    }
}

// ------- context partials + per-row sum of exp(K), no max-sub needed --------
// K values are O(0.01): exp without max subtraction is exact-safe in fp32.
__global__ __launch_bounds__(256) void ctx_partial(
    const float* __restrict__ Kb, const float* __restrict__ Vb,
    float* __restrict__ ctxp)
{
    const int nh = blockIdx.y;                 // 32
    const int sp = blockIdx.x;                 // 49
    const int n = nh >> 3, h = nh & 7;
    __shared__ float Kt[HK][260];
    __shared__ float Vt[HV][260];
    const int t = threadIdx.x;
    const int l0 = sp*256;
    const float* Kp = Kb + ((size_t)(n*KCC + h*HK))*LL + l0;
    const float* Vp = Vb + ((size_t)(n*VCC + h*HV))*LL + l0;
#pragma unroll
    for (int m = 0; m < HK; ++m) Kt[m][t] = __expf(Kp[(size_t)m*LL + t]);
#pragma unroll
    for (int m = 0; m < HV; ++m) Vt[m][t] = Vp[(size_t)m*LL + t];
    __syncthreads();

    const int kk = t >> 4, v0 = t & 15;
    float acc0 = 0.f, acc1 = 0.f, asum = 0.f;
#pragma unroll 2
    for (int j = 0; j < 256; j += 4) {
        float4 kv = *reinterpret_cast<const float4*>(&Kt[kk][j]);
        float4 va = *reinterpret_cast<const float4*>(&Vt[v0][j]);
        float4 vb = *reinterpret_cast<const float4*>(&Vt[v0+16][j]);
        acc0 += kv.x*va.x; acc0 += kv.y*va.y; acc0 += kv.z*va.z; acc0 += kv.w*va.w;
        acc1 += kv.x*vb.x; acc1 += kv.y*vb.y; acc1 += kv.z*vb.z; acc1 += kv.w*vb.w;
        asum += kv.x + kv.y + kv.z + kv.w;
    }
    float* cp = ctxp + ((size_t)nh*CTXSPLIT + sp)*CTXSTR;
    cp[kk*HV + v0]      = acc0;
    cp[kk*HV + v0 + 16] = acc1;
    if (v0 == 0) cp[512 + kk] = asum;
}

// ------- reduce partials and normalize by per-row sum ------------------------
__global__ void ctx_reduce(const float* __restrict__ ctxp, float* __restrict__ ctx)
{
    const int idx = blockIdx.x*256 + threadIdx.x;   // 16384
    const int nh = idx >> 9;
    const int p  = idx & 511;
    const int k  = p >> 5;
    float s = 0.f, se = 0.f;
    for (int sp = 0; sp < CTXSPLIT; ++sp) {
        const float* cp = ctxp + ((size_t)nh*CTXSPLIT + sp)*CTXSTR;
        s  += cp[p];
        se += cp[512 + k];
    }
    ctx[idx] = s / se;
}

// ------- attended with fused Q channel-softmax; ctx via scalar loads --------
__global__ __launch_bounds__(256) void attended_kernel(
    const float* __restrict__ ctx, const float* __restrict__ Qb,
    float* __restrict__ agg)
{
    const int nh = blockIdx.y;
    const int n = nh >> 3, h = nh & 7;
    const int l = blockIdx.x*256 + threadIdx.x;
    const float* __restrict__ cl = ctx + (size_t)nh*512;   // uniform -> s_load

    const float* Qp = Qb + ((size_t)(n*KCC + h*HK))*LL + l;
    float q[HK];
    float mx = -1e30f;
#pragma unroll
    for (int k = 0; k < HK; ++k) { q[k] = Qp[(size_t)k*LL]; mx = fmaxf(mx, q[k]); }
    float s = 0.f;
#pragma unroll
    for (int k = 0; k < HK; ++k) { q[k] = __expf(q[k] - mx); s += q[k]; }
    const float inv = 1.f / s;
#pragma unroll
    for (int k = 0; k < HK; ++k) q[k] *= inv;

    float* ap = agg + ((size_t)(n*VCC + h*HV))*LL + l;
#pragma unroll 4
    for (int v = 0; v < HV; ++v) {
        float acc = 0.f;
#pragma unroll
        for (int k = 0; k < HK; ++k) acc += q[k] * cl[k*HV + v];
        ap[(size_t)v*LL] = acc;
    }
}

// ------- pw2 of reproj + residual + LN partials, LDS weights, 2 l/thread ----
__global__ __launch_bounds__(256) void pw2r_v2(
    const float* __restrict__ in,    // dwr [N][32][L]
    const float* __restrict__ w,     // [256][32]
    const float* __restrict__ b,     // [256]
    const float* __restrict__ resid, // input_ [N][256][L]
    float* __restrict__ xout,        // [N][256][L]
    float* __restrict__ part)        // [2 * 400]
{
    const int oz = blockIdx.z;       // 0..3
    __shared__ float wl[64*MIDC];
    __shared__ float red[256];
    const int t = threadIdx.x;
    {
        const float4* src = reinterpret_cast<const float4*>(w + (size_t)oz*64*MIDC);
        float4* dst = reinterpret_cast<float4*>(wl);
        for (int i = t; i < 64*MIDC/4; i += 256) dst[i] = src[i];
    }
    __syncthreads();

    const int n = blockIdx.y;
    const int l = blockIdx.x*512 + 2*t;
    const bool active = (l < LL);

    float r0[MIDC], r1[MIDC];
    const float* ip = in + (size_t)n*MIDC*LL + l;
    if (active) {
#pragma unroll
        for (int m = 0; m < MIDC; ++m) {
            float2 x = *reinterpret_cast<const float2*>(ip + (size_t)m*LL);
            r0[m] = x.x; r1[m] = x.y;
        }
    } else {
#pragma unroll
        for (int m = 0; m < MIDC; ++m) { r0[m] = 0.f; r1[m] = 0.f; }
    }

    const float* __restrict__ bz = b + oz*64;
    const float* rp = resid + ((size_t)n*CIN + oz*64)*LL + l;
    float* xp = xout + ((size_t)n*CIN + oz*64)*LL + l;
    float s1 = 0.f, s2 = 0.f;
    for (int o = 0; o < 64; ++o) {
        const float4* wp = reinterpret_cast<const float4*>(&wl[o*MIDC]);
        float acc0 = 0.f, acc1 = 0.f;
#pragma unroll
        for (int mq = 0; mq < 8; ++mq) {
            float4 wv = wp[mq];
            acc0 += wv.x*r0[4*mq+0] + wv.y*r0[4*mq+1] + wv.z*r0[4*mq+2] + wv.w*r0[4*mq+3];
            acc1 += wv.x*r1[4*mq+0] + wv.y*r1[4*mq+1] + wv.z*r1[4*mq+2] + wv.w*r1[4*mq+3];
        }
        if (active) {
            float2 rr = *reinterpret_cast<const float2*>(rp + (size_t)o*LL);
            acc0 += bz[o] + rr.x;
            acc1 += bz[o] + rr.y;
            float2 o2 = { acc0, acc1 };
            *reinterpret_cast<float2*>(xp + (size_t)o*LL) = o2;
            s1 += acc0 + acc1; s2 += acc0*acc0 + acc1*acc1;
        }
    }
    const int bid = (blockIdx.y*gridDim.x + blockIdx.x)*4 + oz;   // < 400
    red[t] = s1; __syncthreads();
    for (int s = 128; s > 0; s >>= 1) { if (t < s) red[t] += red[t+s]; __syncthreads(); }
    if (t == 0) part[2*bid] = red[0];
    __syncthreads();
    red[t] = s2; __syncthreads();
    for (int s = 128; s > 0; s >>= 1) { if (t < s) red[t] += red[t+s]; __syncthreads(); }
    if (t == 0) part[2*bid + 1] = red[0];
}

__global__ void stats_kernel(const float* __restrict__ part, int nblocks,
                             float* __restrict__ stats)
{
    __shared__ float r1[256], r2[256];
    const int t = threadIdx.x;
    float s1 = 0.f, s2 = 0.f;
    for (int i = t; i < nblocks; i += 256) { s1 += part[2*i]; s2 += part[2*i+1]; }
    r1[t] = s1; r2[t] = s2; __syncthreads();
    for (int s = 128; s > 0; s >>= 1) { if (t < s) { r1[t] += r1[t+s]; r2[t] += r2[t+s]; } __syncthreads(); }
    if (t == 0) {
        const float M = (float)NB*CIN*LL;
        const float mu = r1[0]/M;
        const float var = r2[0]/M - mu*mu;
        stats[0] = mu;
        stats[1] = 1.0f/sqrtf(var + EPSV);
    }
}

__global__ __launch_bounds__(256) void norm_kernel(
    const float* __restrict__ x, const float* __restrict__ stats,
    float* __restrict__ out)
{
    const float mu = stats[0], inv = stats[1];
    const size_t total = (size_t)NB*CIN*LL;   // divisible by 4
    for (size_t i = ((size_t)blockIdx.x*256 + threadIdx.x)*4; i < total;
         i += (size_t)gridDim.x*256*4) {
        float4 v = *reinterpret_cast<const float4*>(x + i);
        float4 o;
        o.x = (v.x-mu)*inv; o.y = (v.y-mu)*inv; o.z = (v.z-mu)*inv; o.w = (v.w-mu)*inv;
        *reinterpret_cast<float4*>(out + i) = o;
    }
}

// ------------------------------- launcher ------------------------------------
extern "C" void kernel_launch(void* const* d_in, const int* in_sizes, int n_in,
                              void* d_out, int out_size, void* d_ws, size_t ws_size,
                              hipStream_t stream) {
    const float* input   = (const float*)d_in[0];
    const float* k_pw1_w = (const float*)d_in[1];
    const float* k_pw1_b = (const float*)d_in[2];
    const float* k_dw_w  = (const float*)d_in[3];
    const float* k_dw_b  = (const float*)d_in[4];
    const float* k_pw2_w = (const float*)d_in[5];
    const float* k_pw2_b = (const float*)d_in[6];
    const float* q_pw1_w = (const float*)d_in[7];
    const float* q_pw1_b = (const float*)d_in[8];
    const float* q_dw_w  = (const float*)d_in[9];
    const float* q_dw_b  = (const float*)d_in[10];
    const float* q_pw2_w = (const float*)d_in[11];
    const float* q_pw2_b = (const float*)d_in[12];
    const float* v_pw1_w = (const float*)d_in[13];
    const float* v_pw1_b = (const float*)d_in[14];
    const float* v_dw_w  = (const float*)d_in[15];
    const float* v_dw_b  = (const float*)d_in[16];
    const float* v_pw2_w = (const float*)d_in[17];
    const float* v_pw2_b = (const float*)d_in[18];
    const float* r_pw1_w = (const float*)d_in[19];
    const float* r_pw1_b = (const float*)d_in[20];
    const float* r_dw_w  = (const float*)d_in[21];
    const float* r_dw_b  = (const float*)d_in[22];
    const float* r_pw2_w = (const float*)d_in[23];
    const float* r_pw2_b = (const float*)d_in[24];

    float* ws = (float*)d_ws;
    const size_t N32L = (size_t)NB*MIDC*LL;     // 1,605,632
    const size_t NKL  = (size_t)NB*KCC*LL;      // 6,422,528
    const size_t NVL  = (size_t)NB*VCC*LL;      // 12,845,056

    float* midk = ws;
    float* midq = midk + N32L;
    float* midv = midq + N32L;
    float* dk   = ws + 3*N32L;
    float* dq   = dk + N32L;
    float* dv   = dq + N32L;
    float* Kb   = ws + 6*N32L;
    float* Qb   = Kb + NKL;
    float* Vb   = Qb + NKL;
    float* agg  = Vb;          // V dead after ctx_partial
    float* xb   = Kb;          // K,Q dead after attended; spans exactly NVL
    float* ctxp = dk;          // 852,992 <= N32L; dk dead after pw2_v2
    float* ctx  = dv;          // dv dead after pw2_v2
    float* part = dv + 20000;
    float* statsp = dv + 24000;
    float* midr = midk;        // mids dead after dw_fused
    float* dwr  = dk;          // ctxp dead after ctx_reduce
    float* wt   = (float*)d_out;   // 4*8192 floats; overwritten by norm_kernel

    // weight transpose for pw1 (linear LDS fill later)
    {
        Quad w = {{k_pw1_w, q_pw1_w, v_pw1_w, r_pw1_w}};
        transpose_w<<<128, 256, 0, stream>>>(w, wt);
    }

    // k/q/v projections
    {
        Pw1A a;
        a.wt[0]=wt; a.wt[1]=wt+8192; a.wt[2]=wt+16384;
        a.b[0]=k_pw1_b; a.b[1]=q_pw1_b; a.b[2]=v_pw1_b;
        a.out[0]=midk; a.out[1]=midq; a.out[2]=midv;
        pw1_v2<<<dim3(25, NB, 3), 256, 0, stream>>>(input, a);
    }
    {
        DwA a;
        a.in[0]=midk; a.in[1]=midq; a.in[2]=midv;
        a.w[0]=k_dw_w; a.w[1]=q_dw_w; a.w[2]=v_dw_w;
        a.b[0]=k_dw_b; a.b[1]=q_dw_b; a.b[2]=v_dw_b;
        a.out[0]=dk; a.out[1]=dq; a.out[2]=dv;
        dw_fused<<<dim3(TT, NB*MIDC, 3), 256, 0, stream>>>(a);
    }
    {
        Pw2A a;
        a.in[0]=dk; a.in[1]=dq; a.in[2]=dv;
        a.w[0]=k_pw2_w; a.w[1]=q_pw2_w; a.w[2]=v_pw2_w;
        a.b[0]=k_pw2_b; a.b[1]=q_pw2_b; a.b[2]=v_pw2_b;
        a.out[0]=Kb; a.out[1]=Qb; a.out[2]=Vb;
        a.ocn[0]=KCC; a.ocn[1]=KCC; a.ocn[2]=VCC;
        pw2_v2<<<dim3(25, NB, 8), 256, 0, stream>>>(a);
    }

    // attention
    ctx_partial<<<dim3(CTXSPLIT, NB*HC), 256, 0, stream>>>(Kb, Vb, ctxp);
    ctx_reduce<<<64, 256, 0, stream>>>(ctxp, ctx);
    attended_kernel<<<dim3(49, NB*HC), 256, 0, stream>>>(ctx, Qb, agg);

    // reprojection + residual + global layernorm
    {
        Pw1A a;
        a.wt[0]=wt+24576; a.b[0]=r_pw1_b; a.out[0]=midr;
        a.wt[1]=a.wt[0];  a.b[1]=a.b[0];  a.out[1]=midr;
        a.wt[2]=a.wt[0];  a.b[2]=a.b[0];  a.out[2]=midr;
        pw1_v2<<<dim3(25, NB, 1), 256, 0, stream>>>(agg, a);
    }
    {
        DwA a;
        a.in[0]=midr; a.w[0]=r_dw_w; a.b[0]=r_dw_b; a.out[0]=dwr;
        a.in[1]=midr; a.w[1]=r_dw_w; a.b[1]=r_dw_b; a.out[1]=dwr;
        a.in[2]=midr; a.w[2]=r_dw_w; a.b[2]=r_dw_b; a.out[2]=dwr;
        dw_fused<<<dim3(TT, NB*MIDC, 1), 256, 0, stream>>>(a);
    }
    pw2r_v2<<<dim3(25, NB, 4), 256, 0, stream>>>(dwr, r_pw2_w, r_pw2_b, input, xb, part);
    stats_kernel<<<1, 256, 0, stream>>>(part, 4*25*NB, statsp);
    norm_kernel<<<2048, 256, 0, stream>>>(xb, statsp, (float*)d_out);
}

// Round 5
// 262.048 us; speedup vs baseline: 1.6095x; 1.4840x over previous
//
#include <hip/hip_runtime.h>
#include <cstddef>

// Problem constants
#define NB   4
#define CIN  256
#define TT   16
#define HH   28
#define WW   28
#define LL   12544           // 16*28*28 = 784*16
#define NTAU 784              // LL/16
#define MIDC 32
#define KCC  128
#define VCC  256
#define HC   8
#define HK   16
#define HV   32
#define CTXSPLIT 49
#define CTXSTR 544
#define EPSV 1e-5f

typedef __attribute__((ext_vector_type(8))) short bf16x8;
typedef __attribute__((ext_vector_type(4))) float f32x4;

__device__ __forceinline__ float b2f(unsigned short u) {
    return __builtin_bit_cast(float, ((unsigned int)u) << 16);
}
__device__ __forceinline__ unsigned short f2b(float f) {
    unsigned int u = __builtin_bit_cast(unsigned int, f);
    u += 0x7FFFu + ((u >> 16) & 1u);          // RNE
    return (unsigned short)(u >> 16);
}

// sizes (elements)
#define XTF_N_STRIDE 3211264ull        // 784*8*512 shorts per sample
#define DTF_N_STRIDE 401408ull         // 784*512 shorts per sample (per set)
#define MID_SET_STRIDE 1605632ull      // 4*32*12544 floats per set

struct WconvA { const float* w1[4]; const float* w2[4]; };
struct Pw1M  { const short* wt[3]; const float* b[3]; float* out[3]; };
struct DwA   { const float* in[3]; const float* w[3]; const float* b[3]; float* out[3]; };
struct Pw2M  { const short* w2f; const short* dtf; const float* b[3]; unsigned short* out[3]; };

// ---- weights -> fragment-major bf16 tables --------------------------------
// w1f: tile TI=set*2+mt in [0,8): elem (L,j) = w1[set][16*mt+(L&15)][32*kap+8*(L>>4)+j]
// w2f: tile TI in [0,48) (k:0-7,q:8-15,v:16-31,r:32-47): (L,j)=w2[set][16*mtl+(L&15)][8*(L>>4)+j]
__global__ __launch_bounds__(256) void wconv_kernel(WconvA a, short* __restrict__ w1f,
                                                    short* __restrict__ w2f)
{
    const int g = blockIdx.x*256 + threadIdx.x;
    if (g < 4096) {
        const int L = g & 63, kap = (g >> 6) & 7, mt = (g >> 9) & 1, set = g >> 10;
        const int m = 16*mt + (L & 15);
        const int c0 = 32*kap + 8*(L >> 4);
        const float* wp = a.w1[set] + m*CIN + c0;
#pragma unroll
        for (int j = 0; j < 8; ++j) w1f[(size_t)g*8 + j] = (short)f2b(wp[j]);
    } else if (g < 4096 + 3072) {
        const int g2 = g - 4096;
        const int L = g2 & 63, mtg = g2 >> 6;
        int set, mtl;
        if (mtg < 8)       { set = 0; mtl = mtg; }
        else if (mtg < 16) { set = 1; mtl = mtg - 8; }
        else if (mtg < 32) { set = 2; mtl = mtg - 16; }
        else               { set = 3; mtl = mtg - 32; }
        const int m = 16*mtl + (L & 15);
        const int c0 = 8*(L >> 4);
        const float* wp = a.w2[set] + m*MIDC + c0;
#pragma unroll
        for (int j = 0; j < 8; ++j) w2f[(size_t)g2*8 + j] = (short)f2b(wp[j]);
    }
}

// ---- input fp32 [N][256][L] -> xtf bf16 frag-major -------------------------
// flat = n*XTF_N_STRIDE + ((tau*8+kap)*512 + L*8 + j); elem = in[n][32k+8(L>>4)+j][16tau+(L&15)]
__global__ __launch_bounds__(256) void transp_in(const float* __restrict__ in,
                                                 short* __restrict__ xtf)
{
    const int n = blockIdx.y;
    const int tau = blockIdx.x >> 1;
    const int idx = (blockIdx.x & 1)*256 + threadIdx.x;    // 0..511
    const int kap = idx >> 6, L = idx & 63;
    const int l = 16*tau + (L & 15);
    const int c0 = 32*kap + 8*(L >> 4);
    const float* ip = in + ((size_t)n*CIN + c0)*LL + l;
    bf16x8 vv;
#pragma unroll
    for (int j = 0; j < 8; ++j) vv[j] = (short)f2b(ip[(size_t)j*LL]);
    *reinterpret_cast<bf16x8*>(xtf + (size_t)n*XTF_N_STRIDE +
                               ((size_t)(tau*8 + kap)*512 + L*8)) = vv;
}

// ---- pw1 MFMA: [32 x 256] @ [256 x L] + b -> mid fp32 [n][32][L] -----------
__global__ __launch_bounds__(256) void pw1_mfma(const short* __restrict__ xtf, Pw1M a)
{
    const int z = blockIdx.z, n = blockIdx.y, bx = blockIdx.x;
    const int t = threadIdx.x, wid = t >> 6, lane = t & 63;
    const int mt = wid & 1, lh = wid >> 1;
    const int tau0 = bx*8 + lh*4;
    const short* wt = a.wt[z];
    const short* xb = xtf + (size_t)n*XTF_N_STRIDE;

    f32x4 acc[4];
#pragma unroll
    for (int i = 0; i < 4; ++i)
#pragma unroll
        for (int r = 0; r < 4; ++r) acc[i][r] = 0.f;

    for (int kap = 0; kap < 8; ++kap) {
        bf16x8 afr = *reinterpret_cast<const bf16x8*>(wt + ((mt*8 + kap)*512 + lane*8));
#pragma unroll
        for (int i = 0; i < 4; ++i) {
            bf16x8 bfr = *reinterpret_cast<const bf16x8*>(
                xb + ((size_t)((tau0 + i)*8 + kap)*512 + lane*8));
            acc[i] = __builtin_amdgcn_mfma_f32_16x16x32_bf16(afr, bfr, acc[i], 0, 0, 0);
        }
    }
    const float* bb = a.b[z];
    float* op = a.out[z] + (size_t)n*MIDC*LL;
    const int col = lane & 15;
    const int m0 = mt*16 + (lane >> 4)*4;
#pragma unroll
    for (int r = 0; r < 4; ++r) {
        const float bv = bb[m0 + r];
#pragma unroll
        for (int i = 0; i < 4; ++i)
            op[(size_t)(m0 + r)*LL + (tau0 + i)*16 + col] = acc[i][r] + bv;
    }
}

// ---- depthwise 3x3x3, pad 1 (fp32, unchanged) -------------------------------
__global__ __launch_bounds__(256) void dw_fused(DwA a)
{
    const int z  = blockIdx.z;
    const int nm = blockIdx.y;             // n*32 + m
    const int m  = nm & (MIDC-1);
    const int tz = blockIdx.x;
    __shared__ float wl[27];
    if (threadIdx.x < 27) wl[threadIdx.x] = a.w[z][m*27 + threadIdx.x];
    __syncthreads();
    const float bias = a.b[z][m];
    const float* ip = a.in[z] + (size_t)nm*LL;
    float* op = a.out[z] + (size_t)nm*LL + tz*HH*WW;

    for (int hw = threadIdx.x; hw < HH*WW; hw += 256) {
        const int y = hw / WW, x = hw - y*WW;
        float acc = bias;
#pragma unroll
        for (int dz = 0; dz < 3; ++dz) {
            const int zz = tz + dz - 1;
            if (zz < 0 || zz >= TT) continue;
#pragma unroll
            for (int dy = 0; dy < 3; ++dy) {
                const int yy = y + dy - 1;
                if (yy < 0 || yy >= HH) continue;
#pragma unroll
                for (int dx = 0; dx < 3; ++dx) {
                    const int xx = x + dx - 1;
                    if (xx < 0 || xx >= WW) continue;
                    acc += wl[(dz*3+dy)*3+dx] * ip[((size_t)zz*HH + yy)*WW + xx];
                }
            }
        }
        op[hw] = acc;
    }
}

// ---- d fp32 [set][n][32][L] -> dtf bf16 frag-major --------------------------
__global__ __launch_bounds__(256) void dt_transp(const float* __restrict__ d,
                                                 short* __restrict__ dtf)
{
    const int set = blockIdx.z, n = blockIdx.y;
    const int t = threadIdx.x;
    const int tau = blockIdx.x*4 + (t >> 6);
    const int L = t & 63;
    const int l = 16*tau + (L & 15);
    const int c0 = 8*(L >> 4);
    const float* ip = d + ((size_t)set*NB + n)*MIDC*LL + (size_t)c0*LL + l;
    bf16x8 vv;
#pragma unroll
    for (int j = 0; j < 8; ++j) vv[j] = (short)f2b(ip[(size_t)j*LL]);
    *reinterpret_cast<bf16x8*>(dtf + ((size_t)set*NB + n)*DTF_N_STRIDE +
                               (size_t)tau*512 + L*8) = vv;
}

// ---- pw2 MFMA: [OC x 32] @ [32 x L] + b -> K/Q/V bf16 [n][OC][L] ------------
// z: 0-1 k-chunks, 2-3 q-chunks, 4-7 v-chunks (64 out-channels per chunk)
__global__ __launch_bounds__(256) void pw2_mfma(Pw2M a)
{
    const int z = blockIdx.z, n = blockIdx.y, bx = blockIdx.x;
    int set, chunk;
    if (z < 2)      { set = 0; chunk = z; }
    else if (z < 4) { set = 1; chunk = z - 2; }
    else            { set = 2; chunk = z - 4; }
    const int OC   = (set == 2) ? 256 : 128;
    const int off2 = (set == 0) ? 0 : (set == 1) ? 8 : 16;

    const int t = threadIdx.x, wid = t >> 6, lane = t & 63;
    const int mtile = chunk*4 + wid;
    bf16x8 afr = *reinterpret_cast<const bf16x8*>(
        a.w2f + ((size_t)(off2 + mtile)*512 + lane*8));
    const short* db = a.dtf + ((size_t)set*NB + n)*DTF_N_STRIDE;

    f32x4 acc[4];
#pragma unroll
    for (int i = 0; i < 4; ++i) {
#pragma unroll
        for (int r = 0; r < 4; ++r) acc[i][r] = 0.f;
        bf16x8 bfr = *reinterpret_cast<const bf16x8*>(db + (size_t)(bx*4 + i)*512 + lane*8);
        acc[i] = __builtin_amdgcn_mfma_f32_16x16x32_bf16(afr, bfr, acc[i], 0, 0, 0);
    }
    const float* bb = a.b[set];
    unsigned short* op = a.out[set] + (size_t)n*OC*LL;
    const int col = lane & 15;
    const int m0 = 16*mtile + (lane >> 4)*4;
#pragma unroll
    for (int r = 0; r < 4; ++r) {
        const float bv = bb[m0 + r];
#pragma unroll
        for (int i = 0; i < 4; ++i)
            op[(size_t)(m0 + r)*LL + (bx*4 + i)*16 + col] = f2b(acc[i][r] + bv);
    }
}

// ---- context partials over 49 L-tiles (bf16 in), + per-row exp-sums ---------
__global__ __launch_bounds__(256) void ctx_partial(
    const unsigned short* __restrict__ Kb, const unsigned short* __restrict__ Vb,
    float* __restrict__ ctxp)
{
    const int nh = blockIdx.y;
    const int sp = blockIdx.x;
    const int n = nh >> 3, h = nh & 7;
    __shared__ float Kt[HK][260];
    __shared__ float Vt[HV][260];
    const int t = threadIdx.x;
    const int l0 = sp*256;
    const unsigned short* Kp = Kb + ((size_t)(n*KCC + h*HK))*LL + l0;
    const unsigned short* Vp = Vb + ((size_t)(n*VCC + h*HV))*LL + l0;
#pragma unroll
    for (int m = 0; m < HK; ++m) Kt[m][t] = __expf(b2f(Kp[(size_t)m*LL + t]));
#pragma unroll
    for (int m = 0; m < HV; ++m) Vt[m][t] = b2f(Vp[(size_t)m*LL + t]);
    __syncthreads();

    const int kk = t >> 4, v0 = t & 15;
    float acc0 = 0.f, acc1 = 0.f, asum = 0.f;
#pragma unroll 2
    for (int j = 0; j < 256; j += 4) {
        float4 kv = *reinterpret_cast<const float4*>(&Kt[kk][j]);
        float4 va = *reinterpret_cast<const float4*>(&Vt[v0][j]);
        float4 vb = *reinterpret_cast<const float4*>(&Vt[v0+16][j]);
        acc0 += kv.x*va.x; acc0 += kv.y*va.y; acc0 += kv.z*va.z; acc0 += kv.w*va.w;
        acc1 += kv.x*vb.x; acc1 += kv.y*vb.y; acc1 += kv.z*vb.z; acc1 += kv.w*vb.w;
        asum += kv.x + kv.y + kv.z + kv.w;
    }
    float* cp = ctxp + ((size_t)nh*CTXSPLIT + sp)*CTXSTR;
    cp[kk*HV + v0]      = acc0;
    cp[kk*HV + v0 + 16] = acc1;
    if (v0 == 0) cp[512 + kk] = asum;
}

__global__ void ctx_reduce(const float* __restrict__ ctxp, float* __restrict__ ctx)
{
    const int idx = blockIdx.x*256 + threadIdx.x;   // 16384
    const int nh = idx >> 9;
    const int p  = idx & 511;
    const int k  = p >> 5;
    float s = 0.f, se = 0.f;
    for (int sp = 0; sp < CTXSPLIT; ++sp) {
        const float* cp = ctxp + ((size_t)nh*CTXSPLIT + sp)*CTXSTR;
        s  += cp[p];
        se += cp[512 + k];
    }
    ctx[idx] = s / se;
}

// ---- attended (fused Q-softmax), emits agg in pw1 frag layout ---------------
__global__ __launch_bounds__(256) void attended_kernel(
    const float* __restrict__ ctx, const unsigned short* __restrict__ Qb,
    short* __restrict__ aggf)
{
    const int nh = blockIdx.y;
    const int n = nh >> 3, h = nh & 7;
    const int l = blockIdx.x*256 + threadIdx.x;
    const float* __restrict__ cl = ctx + (size_t)nh*512;

    const unsigned short* Qp = Qb + ((size_t)(n*KCC + h*HK))*LL + l;
    float q[HK];
    float mx = -1e30f;
#pragma unroll
    for (int k = 0; k < HK; ++k) { q[k] = b2f(Qp[(size_t)k*LL]); mx = fmaxf(mx, q[k]); }
    float s = 0.f;
#pragma unroll
    for (int k = 0; k < HK; ++k) { q[k] = __expf(q[k] - mx); s += q[k]; }
    const float inv = 1.f / s;
#pragma unroll
    for (int k = 0; k < HK; ++k) q[k] *= inv;

    float av[HV];
#pragma unroll 4
    for (int v = 0; v < HV; ++v) {
        float acc = 0.f;
#pragma unroll
        for (int k = 0; k < HK; ++k) acc += q[k] * cl[k*HV + v];
        av[v] = acc;
    }
    // frag layout: kap=h, L=(v>>3)*16+(l&15), j=v&7, tau=l>>4
    short* ob = aggf + (size_t)n*XTF_N_STRIDE + ((size_t)((l >> 4)*8 + h))*512;
#pragma unroll
    for (int qd = 0; qd < 4; ++qd) {
        bf16x8 vv;
#pragma unroll
        for (int j = 0; j < 8; ++j) vv[j] = (short)f2b(av[qd*8 + j]);
        *reinterpret_cast<bf16x8*>(ob + (qd*16 + (l & 15))*8) = vv;
    }
}

// ---- pw2r MFMA: reproj + residual + LN partials -----------------------------
__global__ __launch_bounds__(256) void pw2r_mfma(
    const short* __restrict__ dtf, const short* __restrict__ w2f,
    const float* __restrict__ bias, const float* __restrict__ resid,
    float* __restrict__ xout, float* __restrict__ part)
{
    const int z = blockIdx.z, n = blockIdx.y, bx = blockIdx.x;
    const int t = threadIdx.x, wid = t >> 6, lane = t & 63;
    const int mtile = z*4 + wid;
    bf16x8 afr = *reinterpret_cast<const bf16x8*>(
        w2f + ((size_t)(32 + mtile)*512 + lane*8));
    const short* db = dtf + (size_t)n*DTF_N_STRIDE;

    f32x4 acc[4];
#pragma unroll
    for (int i = 0; i < 4; ++i) {
#pragma unroll
        for (int r = 0; r < 4; ++r) acc[i][r] = 0.f;
        bf16x8 bfr = *reinterpret_cast<const bf16x8*>(db + (size_t)(bx*4 + i)*512 + lane*8);
        acc[i] = __builtin_amdgcn_mfma_f32_16x16x32_bf16(afr, bfr, acc[i], 0, 0, 0);
    }
    const int col = lane & 15;
    const int m0 = 16*mtile + (lane >> 4)*4;
    float s1 = 0.f, s2 = 0.f;
#pragma unroll
    for (int r = 0; r < 4; ++r) {
        const float bv = bias[m0 + r];
#pragma unroll
        for (int i = 0; i < 4; ++i) {
            const size_t off = (size_t)(n*CIN + m0 + r)*LL + (bx*4 + i)*16 + col;
            const float v = acc[i][r] + bv + resid[off];
            xout[off] = v;
            s1 += v; s2 += v*v;
        }
    }
    __shared__ float red[256];
    const int bid = (z*NB + n)*196 + bx;          // < 3136
    red[t] = s1; __syncthreads();
    for (int s = 128; s > 0; s >>= 1) { if (t < s) red[t] += red[t+s]; __syncthreads(); }
    if (t == 0) part[2*bid] = red[0];
    __syncthreads();
    red[t] = s2; __syncthreads();
    for (int s = 128; s > 0; s >>= 1) { if (t < s) red[t] += red[t+s]; __syncthreads(); }
    if (t == 0) part[2*bid + 1] = red[0];
}

__global__ void stats_kernel(const float* __restrict__ part, int nblocks,
                             float* __restrict__ stats)
{
    __shared__ float r1[256], r2[256];
    const int t = threadIdx.x;
    float s1 = 0.f, s2 = 0.f;
    for (int i = t; i < nblocks; i += 256) { s1 += part[2*i]; s2 += part[2*i+1]; }
    r1[t] = s1; r2[t] = s2; __syncthreads();
    for (int s = 128; s > 0; s >>= 1) { if (t < s) { r1[t] += r1[t+s]; r2[t] += r2[t+s]; } __syncthreads(); }
    if (t == 0) {
        const float M = (float)NB*CIN*LL;
        const float mu = r1[0]/M;
        const float var = r2[0]/M - mu*mu;
        stats[0] = mu;
        stats[1] = 1.0f/sqrtf(var + EPSV);
    }
}

__global__ __launch_bounds__(256) void norm_kernel(
    const float* __restrict__ x, const float* __restrict__ stats,
    float* __restrict__ out)
{
    const float mu = stats[0], inv = stats[1];
    const size_t total = (size_t)NB*CIN*LL;
    for (size_t i = ((size_t)blockIdx.x*256 + threadIdx.x)*4; i < total;
         i += (size_t)gridDim.x*256*4) {
        float4 v = *reinterpret_cast<const float4*>(x + i);
        float4 o;
        o.x = (v.x-mu)*inv; o.y = (v.y-mu)*inv; o.z = (v.z-mu)*inv; o.w = (v.w-mu)*inv;
        *reinterpret_cast<float4*>(out + i) = o;
    }
}

// ------------------------------- launcher ------------------------------------
extern "C" void kernel_launch(void* const* d_in, const int* in_sizes, int n_in,
                              void* d_out, int out_size, void* d_ws, size_t ws_size,
                              hipStream_t stream) {
    const float* input   = (const float*)d_in[0];
    const float* k_pw1_w = (const float*)d_in[1];
    const float* k_pw1_b = (const float*)d_in[2];
    const float* k_dw_w  = (const float*)d_in[3];
    const float* k_dw_b  = (const float*)d_in[4];
    const float* k_pw2_w = (const float*)d_in[5];
    const float* k_pw2_b = (const float*)d_in[6];
    const float* q_pw1_w = (const float*)d_in[7];
    const float* q_pw1_b = (const float*)d_in[8];
    const float* q_dw_w  = (const float*)d_in[9];
    const float* q_dw_b  = (const float*)d_in[10];
    const float* q_pw2_w = (const float*)d_in[11];
    const float* q_pw2_b = (const float*)d_in[12];
    const float* v_pw1_w = (const float*)d_in[13];
    const float* v_pw1_b = (const float*)d_in[14];
    const float* v_dw_w  = (const float*)d_in[15];
    const float* v_dw_b  = (const float*)d_in[16];
    const float* v_pw2_w = (const float*)d_in[17];
    const float* v_pw2_b = (const float*)d_in[18];
    const float* r_pw1_w = (const float*)d_in[19];
    const float* r_pw1_b = (const float*)d_in[20];
    const float* r_dw_w  = (const float*)d_in[21];
    const float* r_dw_b  = (const float*)d_in[22];
    const float* r_pw2_w = (const float*)d_in[23];
    const float* r_pw2_b = (const float*)d_in[24];

    // ---- workspace carve (bytes) ----
    char* base = (char*)d_ws;
    // R0 (25,690,112 B): xtf -> d(kqv) -> aggf (sequential tenants)
    short* xtf  = (short*)base;
    float* dbuf = (float*)base;
    short* aggf = (short*)base;
    // R1 (19,267,584 B): mid(kqv) -> {mid_r, d_r, dtf_r}
    float* midb  = (float*)(base + 25690112);
    float* mid_r = midb;
    float* d_r   = (float*)(base + 25690112 + 6422528);
    short* dtf_r = (short*)(base + 25690112 + 12845056);
    // R2 (9,633,792 B): dtf (kqv)
    short* dtf = (short*)(base + 44957696);
    // R3 (51,380,224 B): K,Q,V bf16 -> x fp32
    unsigned short* Kb = (unsigned short*)(base + 54591488);
    unsigned short* Qb = (unsigned short*)(base + 67436544);
    unsigned short* Vb = (unsigned short*)(base + 80281600);
    float* xb = (float*)(base + 54591488);
    // R4 (small)
    char* H = base + 105971712;
    float* ctxp   = (float*)H;                    // 3,411,968 B
    float* ctx    = (float*)(H + 3411968);        // 65,536 B
    float* part   = (float*)(H + 3477504);        // 25,088 B
    float* statsp = (float*)(H + 3502592);        // 64 B
    short* w1f    = (short*)(H + 3502656);        // 65,536 B
    short* w2f    = (short*)(H + 3568192);        // 49,152 B

    // 1. weight fragment tables
    {
        WconvA a;
        a.w1[0]=k_pw1_w; a.w1[1]=q_pw1_w; a.w1[2]=v_pw1_w; a.w1[3]=r_pw1_w;
        a.w2[0]=k_pw2_w; a.w2[1]=q_pw2_w; a.w2[2]=v_pw2_w; a.w2[3]=r_pw2_w;
        wconv_kernel<<<28, 256, 0, stream>>>(a, w1f, w2f);
    }
    // 2. input -> frag-major bf16
    transp_in<<<dim3(1568, NB), 256, 0, stream>>>(input, xtf);
    // 3. pw1 k/q/v (MFMA)
    {
        Pw1M a;
        a.wt[0]=w1f;        a.wt[1]=w1f+8192;   a.wt[2]=w1f+16384;
        a.b[0]=k_pw1_b;     a.b[1]=q_pw1_b;     a.b[2]=v_pw1_b;
        a.out[0]=midb;      a.out[1]=midb+MID_SET_STRIDE; a.out[2]=midb+2*MID_SET_STRIDE;
        pw1_mfma<<<dim3(98, NB, 3), 256, 0, stream>>>(xtf, a);
    }
    // 4. depthwise k/q/v (fp32) -> dbuf (overwrites xtf, now dead)
    {
        DwA a;
        a.in[0]=midb; a.in[1]=midb+MID_SET_STRIDE; a.in[2]=midb+2*MID_SET_STRIDE;
        a.w[0]=k_dw_w; a.w[1]=q_dw_w; a.w[2]=v_dw_w;
        a.b[0]=k_dw_b; a.b[1]=q_dw_b; a.b[2]=v_dw_b;
        a.out[0]=dbuf; a.out[1]=dbuf+MID_SET_STRIDE; a.out[2]=dbuf+2*MID_SET_STRIDE;
        dw_fused<<<dim3(TT, NB*MIDC, 3), 256, 0, stream>>>(a);
    }
    // 5. d -> frag-major bf16
    dt_transp<<<dim3(196, NB, 3), 256, 0, stream>>>(dbuf, dtf);
    // 6. pw2 k/q/v (MFMA) -> K,Q,V bf16
    {
        Pw2M a;
        a.w2f = w2f; a.dtf = dtf;
        a.b[0]=k_pw2_b; a.b[1]=q_pw2_b; a.b[2]=v_pw2_b;
        a.out[0]=Kb; a.out[1]=Qb; a.out[2]=Vb;
        pw2_mfma<<<dim3(196, NB, 8), 256, 0, stream>>>(a);
    }
    // 7-8. context
    ctx_partial<<<dim3(CTXSPLIT, NB*HC), 256, 0, stream>>>(Kb, Vb, ctxp);
    ctx_reduce<<<64, 256, 0, stream>>>(ctxp, ctx);
    // 9. attended -> aggf (frag layout, overwrites dbuf, now dead)
    attended_kernel<<<dim3(49, NB*HC), 256, 0, stream>>>(ctx, Qb, aggf);
    // 10. pw1 r (MFMA)
    {
        Pw1M a;
        a.wt[0]=w1f+24576; a.wt[1]=a.wt[0]; a.wt[2]=a.wt[0];
        a.b[0]=r_pw1_b;    a.b[1]=a.b[0];   a.b[2]=a.b[0];
        a.out[0]=mid_r;    a.out[1]=a.out[0]; a.out[2]=a.out[0];
        pw1_mfma<<<dim3(98, NB, 1), 256, 0, stream>>>(aggf, a);
    }
    // 11. depthwise r
    {
        DwA a;
        a.in[0]=mid_r; a.w[0]=r_dw_w; a.b[0]=r_dw_b; a.out[0]=d_r;
        a.in[1]=a.in[0]; a.w[1]=a.w[0]; a.b[1]=a.b[0]; a.out[1]=a.out[0];
        a.in[2]=a.in[0]; a.w[2]=a.w[0]; a.b[2]=a.b[0]; a.out[2]=a.out[0];
        dw_fused<<<dim3(TT, NB*MIDC, 1), 256, 0, stream>>>(a);
    }
    // 12. d_r -> frag
    dt_transp<<<dim3(196, NB, 1), 256, 0, stream>>>(d_r, dtf_r);
    // 13. pw2 r + residual + LN partials -> x (overwrites K/Q/V, now dead)
    pw2r_mfma<<<dim3(196, NB, 4), 256, 0, stream>>>(dtf_r, w2f, r_pw2_b, input, xb, part);
    // 14-15. global layernorm
    stats_kernel<<<1, 256, 0, stream>>>(part, 3136, statsp);
    norm_kernel<<<2048, 256, 0, stream>>>(xb, statsp, (float*)d_out);
}

// Round 6
// 187.630 us; speedup vs baseline: 2.2479x; 1.3966x over previous
//
#include <hip/hip_runtime.h>
#include <cstddef>

// Problem constants
#define NB   4
#define CIN  256
#define TT   16
#define HH   28
#define WW   28
#define LL   12544           // 16*28*28 = 784*16
#define MIDC 32
#define KCC  128
#define VCC  256
#define HC   8
#define HK   16
#define HV   32
#define CTXSPLIT 49
#define CTXSTR 544
#define EPSV 1e-5f

typedef __attribute__((ext_vector_type(8))) short bf16x8;
typedef __attribute__((ext_vector_type(4))) float f32x4;
typedef __attribute__((ext_vector_type(4))) unsigned short u16x4;

__device__ __forceinline__ float b2f(unsigned short u) {
    return __builtin_bit_cast(float, ((unsigned int)u) << 16);
}
__device__ __forceinline__ unsigned short f2b(float f) {
    unsigned int u = __builtin_bit_cast(unsigned int, f);
    u += 0x7FFFu + ((u >> 16) & 1u);          // RNE
    return (unsigned short)(u >> 16);
}

// sizes (elements)
#define XTF_N_STRIDE 3211264ull        // 784*8*512 shorts per sample
#define DTF_N_STRIDE 401408ull         // 784*512 shorts per sample (per set)
#define MID_SET_STRIDE 1605632ull      // 4*32*12544 elems per set

struct WconvA { const float* w1[4]; const float* w2[4]; };
struct Pw1M  { const short* wt[3]; const float* b[3]; unsigned short* out[3]; };
struct DwA   { const unsigned short* in[3]; const float* w[3]; const float* b[3]; unsigned short* out[3]; };
struct Pw2M  { const short* w2f; const short* dtf; const float* b[3]; unsigned short* out[3]; };

// ---- weights -> fragment-major bf16 tables --------------------------------
__global__ __launch_bounds__(256) void wconv_kernel(WconvA a, short* __restrict__ w1f,
                                                    short* __restrict__ w2f)
{
    const int g = blockIdx.x*256 + threadIdx.x;
    if (g < 4096) {
        const int L = g & 63, kap = (g >> 6) & 7, mt = (g >> 9) & 1, set = g >> 10;
        const int m = 16*mt + (L & 15);
        const int c0 = 32*kap + 8*(L >> 4);
        const float* wp = a.w1[set] + m*CIN + c0;
#pragma unroll
        for (int j = 0; j < 8; ++j) w1f[(size_t)g*8 + j] = (short)f2b(wp[j]);
    } else if (g < 4096 + 3072) {
        const int g2 = g - 4096;
        const int L = g2 & 63, mtg = g2 >> 6;
        int set, mtl;
        if (mtg < 8)       { set = 0; mtl = mtg; }
        else if (mtg < 16) { set = 1; mtl = mtg - 8; }
        else if (mtg < 32) { set = 2; mtl = mtg - 16; }
        else               { set = 3; mtl = mtg - 32; }
        const int m = 16*mtl + (L & 15);
        const int c0 = 8*(L >> 4);
        const float* wp = a.w2[set] + m*MIDC + c0;
#pragma unroll
        for (int j = 0; j < 8; ++j) w2f[(size_t)g2*8 + j] = (short)f2b(wp[j]);
    }
}

// ---- input fp32 [N][256][L] -> xtf bf16 frag-major -------------------------
__global__ __launch_bounds__(256) void transp_in(const float* __restrict__ in,
                                                 short* __restrict__ xtf)
{
    const int n = blockIdx.y;
    const int tau = blockIdx.x >> 1;
    const int idx = (blockIdx.x & 1)*256 + threadIdx.x;    // 0..511
    const int kap = idx >> 6, L = idx & 63;
    const int l = 16*tau + (L & 15);
    const int c0 = 32*kap + 8*(L >> 4);
    const float* ip = in + ((size_t)n*CIN + c0)*LL + l;
    bf16x8 vv;
#pragma unroll
    for (int j = 0; j < 8; ++j) vv[j] = (short)f2b(ip[(size_t)j*LL]);
    *reinterpret_cast<bf16x8*>(xtf + (size_t)n*XTF_N_STRIDE +
                               ((size_t)(tau*8 + kap)*512 + L*8)) = vv;
}

// ---- pw1 MFMA (NS sets share B-frags): [32x256]@[256xL] + b -> mid bf16 ----
template<int NS>
__global__ __launch_bounds__(256) void pw1_mfma_t(const short* __restrict__ xtf, Pw1M a)
{
    const int n = blockIdx.y, bx = blockIdx.x;
    const int t = threadIdx.x, wid = t >> 6, lane = t & 63;
    const int mt = wid & 1, lh = wid >> 1;
    const int tau0 = bx*8 + lh*4;
    const short* xb = xtf + (size_t)n*XTF_N_STRIDE;

    f32x4 acc[NS][4];
#pragma unroll
    for (int s = 0; s < NS; ++s)
#pragma unroll
        for (int i = 0; i < 4; ++i)
#pragma unroll
            for (int r = 0; r < 4; ++r) acc[s][i][r] = 0.f;

    for (int kap = 0; kap < 8; ++kap) {
        bf16x8 bfr[4];
#pragma unroll
        for (int i = 0; i < 4; ++i)
            bfr[i] = *reinterpret_cast<const bf16x8*>(
                xb + ((size_t)((tau0 + i)*8 + kap)*512 + lane*8));
#pragma unroll
        for (int s = 0; s < NS; ++s) {
            bf16x8 afr = *reinterpret_cast<const bf16x8*>(
                a.wt[s] + ((mt*8 + kap)*512 + lane*8));
#pragma unroll
            for (int i = 0; i < 4; ++i)
                acc[s][i] = __builtin_amdgcn_mfma_f32_16x16x32_bf16(afr, bfr[i], acc[s][i], 0, 0, 0);
        }
    }
    const int col = lane & 15;
    const int m0 = mt*16 + (lane >> 4)*4;
#pragma unroll
    for (int s = 0; s < NS; ++s) {
        const float* bb = a.b[s];
        unsigned short* op = a.out[s] + (size_t)n*MIDC*LL;
#pragma unroll
        for (int r = 0; r < 4; ++r) {
            const float bv = bb[m0 + r];
#pragma unroll
            for (int i = 0; i < 4; ++i)
                op[(size_t)(m0 + r)*LL + (tau0 + i)*16 + col] = f2b(acc[s][i][r] + bv);
        }
    }
}

// ---- depthwise 3x3x3, pad 1: register sliding window over t ----------------
struct Row6 { float v[6]; };

__device__ __forceinline__ Row6 load_row(const unsigned short* base, int zz, int yy, int x0)
{
    Row6 r;
    const bool ok = (zz >= 0) && (zz < TT) && (yy >= 0) && (yy < HH);
    if (ok) {
        const unsigned short* p = base + zz*(HH*WW) + yy*WW + x0;
        u16x4 m4 = *reinterpret_cast<const u16x4*>(p);
        r.v[0] = (x0 > 0)  ? b2f(p[-1]) : 0.f;
        r.v[1] = b2f(m4[0]); r.v[2] = b2f(m4[1]);
        r.v[3] = b2f(m4[2]); r.v[4] = b2f(m4[3]);
        r.v[5] = (x0 < 24) ? b2f(p[4]) : 0.f;
    } else {
#pragma unroll
        for (int i = 0; i < 6; ++i) r.v[i] = 0.f;
    }
    return r;
}

__device__ __forceinline__ void acc9(float& a0, float& a1, float& a2, float& a3,
                                     const Row6* rows, const float* w9)
{
#pragma unroll
    for (int dy = 0; dy < 3; ++dy)
#pragma unroll
        for (int dx = 0; dx < 3; ++dx) {
            const float wv = w9[dy*3 + dx];
            a0 = fmaf(wv, rows[dy].v[0 + dx], a0);
            a1 = fmaf(wv, rows[dy].v[1 + dx], a1);
            a2 = fmaf(wv, rows[dy].v[2 + dx], a2);
            a3 = fmaf(wv, rows[dy].v[3 + dx], a3);
        }
}

__global__ __launch_bounds__(256) void dw_reg(DwA a)
{
    const int tid = threadIdx.x;
    if (tid >= 196) return;                  // 7 x-groups * 28 y
    const int z  = blockIdx.z;
    const int nm = blockIdx.y;               // n*32 + m
    const int m  = nm & (MIDC-1);
    const int t0 = blockIdx.x * 8;           // t-half

    const float* wp = a.w[z] + m*27;         // uniform -> s_load
    float wv[27];
#pragma unroll
    for (int i = 0; i < 27; ++i) wv[i] = wp[i];
    const float bias = a.b[z][m];

    const int xg = tid % 7, y = tid / 7;
    const int x0 = xg*4;
    const unsigned short* ip = a.in[z] + (size_t)nm*LL;
    unsigned short* op = a.out[z] + (size_t)nm*LL;

    Row6 win[3][3];
    // plane t0-1 -> slot 0, plane t0 -> slot 1
#pragma unroll
    for (int dy = 0; dy < 3; ++dy) {
        win[0][dy] = load_row(ip, t0-1, y+dy-1, x0);
        win[1][dy] = load_row(ip, t0,   y+dy-1, x0);
    }
#pragma unroll
    for (int tt = 0; tt < 8; ++tt) {
        const int p0 = tt % 3, p1 = (tt+1) % 3, p2 = (tt+2) % 3;
        const int znew = t0 + tt + 1;
        win[p2][0] = load_row(ip, znew, y-1, x0);
        win[p2][1] = load_row(ip, znew, y,   x0);
        win[p2][2] = load_row(ip, znew, y+1, x0);

        float a0 = bias, a1 = bias, a2 = bias, a3 = bias;
        acc9(a0, a1, a2, a3, win[p0], wv);
        acc9(a0, a1, a2, a3, win[p1], wv + 9);
        acc9(a0, a1, a2, a3, win[p2], wv + 18);

        u16x4 o4 = { f2b(a0), f2b(a1), f2b(a2), f2b(a3) };
        *reinterpret_cast<u16x4*>(op + (size_t)(t0+tt)*(HH*WW) + y*WW + x0) = o4;
    }
}

// ---- d bf16 [set][n][32][L] -> dtf bf16 frag-major --------------------------
__global__ __launch_bounds__(256) void dt_transp(const unsigned short* __restrict__ d,
                                                 short* __restrict__ dtf)
{
    const int set = blockIdx.z, n = blockIdx.y;
    const int t = threadIdx.x;
    const int tau = blockIdx.x*4 + (t >> 6);
    const int L = t & 63;
    const int l = 16*tau + (L & 15);
    const int c0 = 8*(L >> 4);
    const unsigned short* ip = d + ((size_t)set*NB + n)*MIDC*LL + (size_t)c0*LL + l;
    bf16x8 vv;
#pragma unroll
    for (int j = 0; j < 8; ++j) vv[j] = (short)ip[(size_t)j*LL];
    *reinterpret_cast<bf16x8*>(dtf + ((size_t)set*NB + n)*DTF_N_STRIDE +
                               (size_t)tau*512 + L*8) = vv;
}

// ---- pw2 MFMA: [OC x 32] @ [32 x L] + b -> K/Q/V bf16 [n][OC][L] ------------
__global__ __launch_bounds__(256) void pw2_mfma(Pw2M a)
{
    const int z = blockIdx.z, n = blockIdx.y, bx = blockIdx.x;
    int set, chunk;
    if (z < 2)      { set = 0; chunk = z; }
    else if (z < 4) { set = 1; chunk = z - 2; }
    else            { set = 2; chunk = z - 4; }
    const int OC   = (set == 2) ? 256 : 128;
    const int off2 = (set == 0) ? 0 : (set == 1) ? 8 : 16;

    const int t = threadIdx.x, wid = t >> 6, lane = t & 63;
    const int mtile = chunk*4 + wid;
    bf16x8 afr = *reinterpret_cast<const bf16x8*>(
        a.w2f + ((size_t)(off2 + mtile)*512 + lane*8));
    const short* db = a.dtf + ((size_t)set*NB + n)*DTF_N_STRIDE;

    f32x4 acc[4];
#pragma unroll
    for (int i = 0; i < 4; ++i) {
#pragma unroll
        for (int r = 0; r < 4; ++r) acc[i][r] = 0.f;
        bf16x8 bfr = *reinterpret_cast<const bf16x8*>(db + (size_t)(bx*4 + i)*512 + lane*8);
        acc[i] = __builtin_amdgcn_mfma_f32_16x16x32_bf16(afr, bfr, acc[i], 0, 0, 0);
    }
    const float* bb = a.b[set];
    unsigned short* op = a.out[set] + (size_t)n*OC*LL;
    const int col = lane & 15;
    const int m0 = 16*mtile + (lane >> 4)*4;
#pragma unroll
    for (int r = 0; r < 4; ++r) {
        const float bv = bb[m0 + r];
#pragma unroll
        for (int i = 0; i < 4; ++i)
            op[(size_t)(m0 + r)*LL + (bx*4 + i)*16 + col] = f2b(acc[i][r] + bv);
    }
}

// ---- context partials over 49 L-tiles (bf16 in), + per-row exp-sums ---------
__global__ __launch_bounds__(256) void ctx_partial(
    const unsigned short* __restrict__ Kb, const unsigned short* __restrict__ Vb,
    float* __restrict__ ctxp)
{
    const int nh = blockIdx.y;
    const int sp = blockIdx.x;
    const int n = nh >> 3, h = nh & 7;
    __shared__ float Kt[HK][260];
    __shared__ float Vt[HV][260];
    const int t = threadIdx.x;
    const int l0 = sp*256;
    const unsigned short* Kp = Kb + ((size_t)(n*KCC + h*HK))*LL + l0;
    const unsigned short* Vp = Vb + ((size_t)(n*VCC + h*HV))*LL + l0;
#pragma unroll
    for (int m = 0; m < HK; ++m) Kt[m][t] = __expf(b2f(Kp[(size_t)m*LL + t]));
#pragma unroll
    for (int m = 0; m < HV; ++m) Vt[m][t] = b2f(Vp[(size_t)m*LL + t]);
    __syncthreads();

    const int kk = t >> 4, v0 = t & 15;
    float acc0 = 0.f, acc1 = 0.f, asum = 0.f;
#pragma unroll 2
    for (int j = 0; j < 256; j += 4) {
        float4 kv = *reinterpret_cast<const float4*>(&Kt[kk][j]);
        float4 va = *reinterpret_cast<const float4*>(&Vt[v0][j]);
        float4 vb = *reinterpret_cast<const float4*>(&Vt[v0+16][j]);
        acc0 += kv.x*va.x; acc0 += kv.y*va.y; acc0 += kv.z*va.z; acc0 += kv.w*va.w;
        acc1 += kv.x*vb.x; acc1 += kv.y*vb.y; acc1 += kv.z*vb.z; acc1 += kv.w*vb.w;
        asum += kv.x + kv.y + kv.z + kv.w;
    }
    float* cp = ctxp + ((size_t)nh*CTXSPLIT + sp)*CTXSTR;
    cp[kk*HV + v0]      = acc0;
    cp[kk*HV + v0 + 16] = acc1;
    if (v0 == 0) cp[512 + kk] = asum;
}

__global__ void ctx_reduce(const float* __restrict__ ctxp, float* __restrict__ ctx)
{
    const int idx = blockIdx.x*256 + threadIdx.x;   // 16384
    const int nh = idx >> 9;
    const int p  = idx & 511;
    const int k  = p >> 5;
    float s = 0.f, se = 0.f;
    for (int sp = 0; sp < CTXSPLIT; ++sp) {
        const float* cp = ctxp + ((size_t)nh*CTXSPLIT + sp)*CTXSTR;
        s  += cp[p];
        se += cp[512 + k];
    }
    ctx[idx] = s / se;
}

// ---- attended (fused Q-softmax), emits agg in pw1 frag layout ---------------
__global__ __launch_bounds__(256) void attended_kernel(
    const float* __restrict__ ctx, const unsigned short* __restrict__ Qb,
    short* __restrict__ aggf)
{
    const int nh = blockIdx.y;
    const int n = nh >> 3, h = nh & 7;
    const int l = blockIdx.x*256 + threadIdx.x;
    const float* __restrict__ cl = ctx + (size_t)nh*512;

    const unsigned short* Qp = Qb + ((size_t)(n*KCC + h*HK))*LL + l;
    float q[HK];
    float mx = -1e30f;
#pragma unroll
    for (int k = 0; k < HK; ++k) { q[k] = b2f(Qp[(size_t)k*LL]); mx = fmaxf(mx, q[k]); }
    float s = 0.f;
#pragma unroll
    for (int k = 0; k < HK; ++k) { q[k] = __expf(q[k] - mx); s += q[k]; }
    const float inv = 1.f / s;
#pragma unroll
    for (int k = 0; k < HK; ++k) q[k] *= inv;

    float av[HV];
#pragma unroll 4
    for (int v = 0; v < HV; ++v) {
        float acc = 0.f;
#pragma unroll
        for (int k = 0; k < HK; ++k) acc += q[k] * cl[k*HV + v];
        av[v] = acc;
    }
    short* ob = aggf + (size_t)n*XTF_N_STRIDE + ((size_t)((l >> 4)*8 + h))*512;
#pragma unroll
    for (int qd = 0; qd < 4; ++qd) {
        bf16x8 vv;
#pragma unroll
        for (int j = 0; j < 8; ++j) vv[j] = (short)f2b(av[qd*8 + j]);
        *reinterpret_cast<bf16x8*>(ob + (qd*16 + (l & 15))*8) = vv;
    }
}

// ---- pw2r MFMA: reproj + residual + LN partials -----------------------------
__global__ __launch_bounds__(256) void pw2r_mfma(
    const short* __restrict__ dtf, const short* __restrict__ w2f,
    const float* __restrict__ bias, const float* __restrict__ resid,
    float* __restrict__ xout, float* __restrict__ part)
{
    const int z = blockIdx.z, n = blockIdx.y, bx = blockIdx.x;
    const int t = threadIdx.x, wid = t >> 6, lane = t & 63;
    const int mtile = z*4 + wid;
    bf16x8 afr = *reinterpret_cast<const bf16x8*>(
        w2f + ((size_t)(32 + mtile)*512 + lane*8));
    const short* db = dtf + (size_t)n*DTF_N_STRIDE;

    f32x4 acc[4];
#pragma unroll
    for (int i = 0; i < 4; ++i) {
#pragma unroll
        for (int r = 0; r < 4; ++r) acc[i][r] = 0.f;
        bf16x8 bfr = *reinterpret_cast<const bf16x8*>(db + (size_t)(bx*4 + i)*512 + lane*8);
        acc[i] = __builtin_amdgcn_mfma_f32_16x16x32_bf16(afr, bfr, acc[i], 0, 0, 0);
    }
    const int col = lane & 15;
    const int m0 = 16*mtile + (lane >> 4)*4;
    float s1 = 0.f, s2 = 0.f;
#pragma unroll
    for (int r = 0; r < 4; ++r) {
        const float bv = bias[m0 + r];
#pragma unroll
        for (int i = 0; i < 4; ++i) {
            const size_t off = (size_t)(n*CIN + m0 + r)*LL + (bx*4 + i)*16 + col;
            const float v = acc[i][r] + bv + resid[off];
            xout[off] = v;
            s1 += v; s2 += v*v;
        }
    }
    __shared__ float red[256];
    const int bid = (z*NB + n)*196 + bx;          // < 3136
    red[t] = s1; __syncthreads();
    for (int s = 128; s > 0; s >>= 1) { if (t < s) red[t] += red[t+s]; __syncthreads(); }
    if (t == 0) part[2*bid] = red[0];
    __syncthreads();
    red[t] = s2; __syncthreads();
    for (int s = 128; s > 0; s >>= 1) { if (t < s) red[t] += red[t+s]; __syncthreads(); }
    if (t == 0) part[2*bid + 1] = red[0];
}

__global__ void stats_kernel(const float* __restrict__ part, int nblocks,
                             float* __restrict__ stats)
{
    __shared__ float r1[256], r2[256];
    const int t = threadIdx.x;
    float s1 = 0.f, s2 = 0.f;
    for (int i = t; i < nblocks; i += 256) { s1 += part[2*i]; s2 += part[2*i+1]; }
    r1[t] = s1; r2[t] = s2; __syncthreads();
    for (int s = 128; s > 0; s >>= 1) { if (t < s) { r1[t] += r1[t+s]; r2[t] += r2[t+s]; } __syncthreads(); }
    if (t == 0) {
        const float M = (float)NB*CIN*LL;
        const float mu = r1[0]/M;
        const float var = r2[0]/M - mu*mu;
        stats[0] = mu;
        stats[1] = 1.0f/sqrtf(var + EPSV);
    }
}

__global__ __launch_bounds__(256) void norm_kernel(
    const float* __restrict__ x, const float* __restrict__ stats,
    float* __restrict__ out)
{
    const float mu = stats[0], inv = stats[1];
    const size_t total = (size_t)NB*CIN*LL;
    for (size_t i = ((size_t)blockIdx.x*256 + threadIdx.x)*4; i < total;
         i += (size_t)gridDim.x*256*4) {
        float4 v = *reinterpret_cast<const float4*>(x + i);
        float4 o;
        o.x = (v.x-mu)*inv; o.y = (v.y-mu)*inv; o.z = (v.z-mu)*inv; o.w = (v.w-mu)*inv;
        *reinterpret_cast<float4*>(out + i) = o;
    }
}

// ------------------------------- launcher ------------------------------------
extern "C" void kernel_launch(void* const* d_in, const int* in_sizes, int n_in,
                              void* d_out, int out_size, void* d_ws, size_t ws_size,
                              hipStream_t stream) {
    const float* input   = (const float*)d_in[0];
    const float* k_pw1_w = (const float*)d_in[1];
    const float* k_pw1_b = (const float*)d_in[2];
    const float* k_dw_w  = (const float*)d_in[3];
    const float* k_dw_b  = (const float*)d_in[4];
    const float* k_pw2_w = (const float*)d_in[5];
    const float* k_pw2_b = (const float*)d_in[6];
    const float* q_pw1_w = (const float*)d_in[7];
    const float* q_pw1_b = (const float*)d_in[8];
    const float* q_dw_w  = (const float*)d_in[9];
    const float* q_dw_b  = (const float*)d_in[10];
    const float* q_pw2_w = (const float*)d_in[11];
    const float* q_pw2_b = (const float*)d_in[12];
    const float* v_pw1_w = (const float*)d_in[13];
    const float* v_pw1_b = (const float*)d_in[14];
    const float* v_dw_w  = (const float*)d_in[15];
    const float* v_dw_b  = (const float*)d_in[16];
    const float* v_pw2_w = (const float*)d_in[17];
    const float* v_pw2_b = (const float*)d_in[18];
    const float* r_pw1_w = (const float*)d_in[19];
    const float* r_pw1_b = (const float*)d_in[20];
    const float* r_dw_w  = (const float*)d_in[21];
    const float* r_dw_b  = (const float*)d_in[22];
    const float* r_pw2_w = (const float*)d_in[23];
    const float* r_pw2_b = (const float*)d_in[24];

    // ---- workspace carve (bytes) ----
    char* base = (char*)d_ws;
    // R0: xtf -> dbuf(kqv bf16) -> aggf (sequential tenants)
    short* xtf  = (short*)base;
    unsigned short* dbuf = (unsigned short*)base;
    short* aggf = (short*)base;
    // R1: mid(kqv bf16) -> {mid_r, d_r, dtf_r}
    unsigned short* midb  = (unsigned short*)(base + 25690112);
    unsigned short* mid_r = midb;
    unsigned short* d_r   = (unsigned short*)(base + 25690112 + 6422528);
    short* dtf_r          = (short*)(base + 25690112 + 12845056);
    // R2: dtf (kqv)
    short* dtf = (short*)(base + 44957696);
    // R3: K,Q,V bf16 -> x fp32
    unsigned short* Kb = (unsigned short*)(base + 54591488);
    unsigned short* Qb = (unsigned short*)(base + 67436544);
    unsigned short* Vb = (unsigned short*)(base + 80281600);
    float* xb = (float*)(base + 54591488);
    // R4 (small)
    char* H = base + 105971712;
    float* ctxp   = (float*)H;                    // 3,411,968 B
    float* ctx    = (float*)(H + 3411968);
    float* part   = (float*)(H + 3477504);
    float* statsp = (float*)(H + 3502592);
    short* w1f    = (short*)(H + 3502656);
    short* w2f    = (short*)(H + 3568192);

    // 1. weight fragment tables
    {
        WconvA a;
        a.w1[0]=k_pw1_w; a.w1[1]=q_pw1_w; a.w1[2]=v_pw1_w; a.w1[3]=r_pw1_w;
        a.w2[0]=k_pw2_w; a.w2[1]=q_pw2_w; a.w2[2]=v_pw2_w; a.w2[3]=r_pw2_w;
        wconv_kernel<<<28, 256, 0, stream>>>(a, w1f, w2f);
    }
    // 2. input -> frag-major bf16
    transp_in<<<dim3(1568, NB), 256, 0, stream>>>(input, xtf);
    // 3. pw1 k/q/v (MFMA, shared B) -> mid bf16
    {
        Pw1M a;
        a.wt[0]=w1f;        a.wt[1]=w1f+8192;   a.wt[2]=w1f+16384;
        a.b[0]=k_pw1_b;     a.b[1]=q_pw1_b;     a.b[2]=v_pw1_b;
        a.out[0]=midb;      a.out[1]=midb+MID_SET_STRIDE; a.out[2]=midb+2*MID_SET_STRIDE;
        pw1_mfma_t<3><<<dim3(98, NB), 256, 0, stream>>>(xtf, a);
    }
    // 4. depthwise k/q/v (register sliding window) -> dbuf bf16
    {
        DwA a;
        a.in[0]=midb; a.in[1]=midb+MID_SET_STRIDE; a.in[2]=midb+2*MID_SET_STRIDE;
        a.w[0]=k_dw_w; a.w[1]=q_dw_w; a.w[2]=v_dw_w;
        a.b[0]=k_dw_b; a.b[1]=q_dw_b; a.b[2]=v_dw_b;
        a.out[0]=dbuf; a.out[1]=dbuf+MID_SET_STRIDE; a.out[2]=dbuf+2*MID_SET_STRIDE;
        dw_reg<<<dim3(2, NB*MIDC, 3), 256, 0, stream>>>(a);
    }
    // 5. d -> frag-major bf16
    dt_transp<<<dim3(196, NB, 3), 256, 0, stream>>>(dbuf, dtf);
    // 6. pw2 k/q/v (MFMA) -> K,Q,V bf16
    {
        Pw2M a;
        a.w2f = w2f; a.dtf = dtf;
        a.b[0]=k_pw2_b; a.b[1]=q_pw2_b; a.b[2]=v_pw2_b;
        a.out[0]=Kb; a.out[1]=Qb; a.out[2]=Vb;
        pw2_mfma<<<dim3(196, NB, 8), 256, 0, stream>>>(a);
    }
    // 7-8. context
    ctx_partial<<<dim3(CTXSPLIT, NB*HC), 256, 0, stream>>>(Kb, Vb, ctxp);
    ctx_reduce<<<64, 256, 0, stream>>>(ctxp, ctx);
    // 9. attended -> aggf (frag layout)
    attended_kernel<<<dim3(49, NB*HC), 256, 0, stream>>>(ctx, Qb, aggf);
    // 10. pw1 r (MFMA) -> mid_r bf16
    {
        Pw1M a;
        a.wt[0]=w1f+24576; a.wt[1]=a.wt[0]; a.wt[2]=a.wt[0];
        a.b[0]=r_pw1_b;    a.b[1]=a.b[0];   a.b[2]=a.b[0];
        a.out[0]=mid_r;    a.out[1]=a.out[0]; a.out[2]=a.out[0];
        pw1_mfma_t<1><<<dim3(98, NB), 256, 0, stream>>>(aggf, a);
    }
    // 11. depthwise r -> d_r bf16
    {
        DwA a;
        a.in[0]=mid_r; a.w[0]=r_dw_w; a.b[0]=r_dw_b; a.out[0]=d_r;
        a.in[1]=a.in[0]; a.w[1]=a.w[0]; a.b[1]=a.b[0]; a.out[1]=a.out[0];
        a.in[2]=a.in[0]; a.w[2]=a.w[0]; a.b[2]=a.b[0]; a.out[2]=a.out[0];
        dw_reg<<<dim3(2, NB*MIDC, 1), 256, 0, stream>>>(a);
    }
    // 12. d_r -> frag
    dt_transp<<<dim3(196, NB, 1), 256, 0, stream>>>(d_r, dtf_r);
    // 13. pw2 r + residual + LN partials -> x fp32
    pw2r_mfma<<<dim3(196, NB, 4), 256, 0, stream>>>(dtf_r, w2f, r_pw2_b, input, xb, part);
    // 14-15. global layernorm
    stats_kernel<<<1, 256, 0, stream>>>(part, 3136, statsp);
    norm_kernel<<<2048, 256, 0, stream>>>(xb, statsp, (float*)d_out);
}

// Round 7
// 187.124 us; speedup vs baseline: 2.2539x; 1.0027x over previous
//
#include <hip/hip_runtime.h>
#include <cstddef>

// Problem constants
#define NB   4
#define CIN  256
#define TT   16
#define HH   28
#define WW   28
#define LL   12544           // 16*28*28 = 784*16
#define MIDC 32
#define KCC  128
#define VCC  256
#define HC   8
#define HK   16
#define HV   32
#define CTXSPLIT 49
#define CTXSTR 544
#define EPSV 1e-5f

typedef __attribute__((ext_vector_type(8))) short bf16x8;
typedef __attribute__((ext_vector_type(4))) float f32x4;
typedef __attribute__((ext_vector_type(4))) unsigned short u16x4;

__device__ __forceinline__ float b2f(unsigned short u) {
    return __builtin_bit_cast(float, ((unsigned int)u) << 16);
}
__device__ __forceinline__ unsigned short f2b(float f) {
    unsigned int u = __builtin_bit_cast(unsigned int, f);
    u += 0x7FFFu + ((u >> 16) & 1u);          // RNE
    return (unsigned short)(u >> 16);
}

// sizes (elements)
#define XTF_N_STRIDE 3211264ull        // 784*8*512 shorts per sample
#define DTF_N_STRIDE 401408ull         // 784*512 shorts per sample (per set)
#define MID_SET_STRIDE 1605632ull      // 4*32*12544 elems per set

struct WconvA { const float* w1[4]; const float* w2[4]; };
struct Pw1M  { const short* wt[3]; const float* b[3]; unsigned short* out[3]; };
struct DwA   { const unsigned short* in[3]; const float* w[3]; const float* b[3]; unsigned short* out[3]; };
struct Pw2M  { const short* w2f; const short* dtf; const float* b[3]; unsigned short* out[3]; };

// ---- weights -> fragment-major bf16 tables --------------------------------
__global__ __launch_bounds__(256) void wconv_kernel(WconvA a, short* __restrict__ w1f,
                                                    short* __restrict__ w2f)
{
    const int g = blockIdx.x*256 + threadIdx.x;
    if (g < 4096) {
        const int L = g & 63, kap = (g >> 6) & 7, mt = (g >> 9) & 1, set = g >> 10;
        const int m = 16*mt + (L & 15);
        const int c0 = 32*kap + 8*(L >> 4);
        const float* wp = a.w1[set] + m*CIN + c0;
#pragma unroll
        for (int j = 0; j < 8; ++j) w1f[(size_t)g*8 + j] = (short)f2b(wp[j]);
    } else if (g < 4096 + 3072) {
        const int g2 = g - 4096;
        const int L = g2 & 63, mtg = g2 >> 6;
        int set, mtl;
        if (mtg < 8)       { set = 0; mtl = mtg; }
        else if (mtg < 16) { set = 1; mtl = mtg - 8; }
        else if (mtg < 32) { set = 2; mtl = mtg - 16; }
        else               { set = 3; mtl = mtg - 32; }
        const int m = 16*mtl + (L & 15);
        const int c0 = 8*(L >> 4);
        const float* wp = a.w2[set] + m*MIDC + c0;
#pragma unroll
        for (int j = 0; j < 8; ++j) w2f[(size_t)g2*8 + j] = (short)f2b(wp[j]);
    }
}

// ---- input fp32 [N][256][L] -> xtf bf16 frag-major -------------------------
__global__ __launch_bounds__(256) void transp_in(const float* __restrict__ in,
                                                 short* __restrict__ xtf)
{
    const int n = blockIdx.y;
    const int tau = blockIdx.x >> 1;
    const int idx = (blockIdx.x & 1)*256 + threadIdx.x;    // 0..511
    const int kap = idx >> 6, L = idx & 63;
    const int l = 16*tau + (L & 15);
    const int c0 = 32*kap + 8*(L >> 4);
    const float* ip = in + ((size_t)n*CIN + c0)*LL + l;
    bf16x8 vv;
#pragma unroll
    for (int j = 0; j < 8; ++j) vv[j] = (short)f2b(ip[(size_t)j*LL]);
    *reinterpret_cast<bf16x8*>(xtf + (size_t)n*XTF_N_STRIDE +
                               ((size_t)(tau*8 + kap)*512 + L*8)) = vv;
}

// ---- pw1 MFMA (NS sets share B-frags): [32x256]@[256xL] + b -> mid bf16 ----
template<int NS>
__global__ __launch_bounds__(256) void pw1_mfma_t(const short* __restrict__ xtf, Pw1M a)
{
    const int n = blockIdx.y, bx = blockIdx.x;
    const int t = threadIdx.x, wid = t >> 6, lane = t & 63;
    const int mt = wid & 1, lh = wid >> 1;
    const int tau0 = bx*8 + lh*4;
    const short* xb = xtf + (size_t)n*XTF_N_STRIDE;

    f32x4 acc[NS][4];
#pragma unroll
    for (int s = 0; s < NS; ++s)
#pragma unroll
        for (int i = 0; i < 4; ++i)
#pragma unroll
            for (int r = 0; r < 4; ++r) acc[s][i][r] = 0.f;

    for (int kap = 0; kap < 8; ++kap) {
        bf16x8 bfr[4];
#pragma unroll
        for (int i = 0; i < 4; ++i)
            bfr[i] = *reinterpret_cast<const bf16x8*>(
                xb + ((size_t)((tau0 + i)*8 + kap)*512 + lane*8));
#pragma unroll
        for (int s = 0; s < NS; ++s) {
            bf16x8 afr = *reinterpret_cast<const bf16x8*>(
                a.wt[s] + ((mt*8 + kap)*512 + lane*8));
#pragma unroll
            for (int i = 0; i < 4; ++i)
                acc[s][i] = __builtin_amdgcn_mfma_f32_16x16x32_bf16(afr, bfr[i], acc[s][i], 0, 0, 0);
        }
    }
    const int col = lane & 15;
    const int m0 = mt*16 + (lane >> 4)*4;
#pragma unroll
    for (int s = 0; s < NS; ++s) {
        const float* bb = a.b[s];
        unsigned short* op = a.out[s] + (size_t)n*MIDC*LL;
#pragma unroll
        for (int r = 0; r < 4; ++r) {
            const float bv = bb[m0 + r];
#pragma unroll
            for (int i = 0; i < 4; ++i)
                op[(size_t)(m0 + r)*LL + (tau0 + i)*16 + col] = f2b(acc[s][i][r] + bv);
        }
    }
}

// ---- depthwise 3x3x3, pad 1: register sliding window over t ----------------
struct Row6 { float v[6]; };

__device__ __forceinline__ Row6 load_row(const unsigned short* base, int zz, int yy, int x0)
{
    Row6 r;
    const bool ok = (zz >= 0) && (zz < TT) && (yy >= 0) && (yy < HH);
    if (ok) {
        const unsigned short* p = base + zz*(HH*WW) + yy*WW + x0;
        u16x4 m4 = *reinterpret_cast<const u16x4*>(p);
        r.v[0] = (x0 > 0)  ? b2f(p[-1]) : 0.f;
        r.v[1] = b2f(m4[0]); r.v[2] = b2f(m4[1]);
        r.v[3] = b2f(m4[2]); r.v[4] = b2f(m4[3]);
        r.v[5] = (x0 < 24) ? b2f(p[4]) : 0.f;
    } else {
#pragma unroll
        for (int i = 0; i < 6; ++i) r.v[i] = 0.f;
    }
    return r;
}

__device__ __forceinline__ void acc9(float& a0, float& a1, float& a2, float& a3,
                                     const Row6* rows, const float* w9)
{
#pragma unroll
    for (int dy = 0; dy < 3; ++dy)
#pragma unroll
        for (int dx = 0; dx < 3; ++dx) {
            const float wv = w9[dy*3 + dx];
            a0 = fmaf(wv, rows[dy].v[0 + dx], a0);
            a1 = fmaf(wv, rows[dy].v[1 + dx], a1);
            a2 = fmaf(wv, rows[dy].v[2 + dx], a2);
            a3 = fmaf(wv, rows[dy].v[3 + dx], a3);
        }
}

__global__ __launch_bounds__(256) void dw_reg(DwA a)
{
    const int tid = threadIdx.x;
    if (tid >= 196) return;                  // 7 x-groups * 28 y
    const int z  = blockIdx.z;
    const int nm = blockIdx.y;               // n*32 + m
    const int m  = nm & (MIDC-1);
    const int t0 = blockIdx.x * 8;           // t-half

    const float* wp = a.w[z] + m*27;         // uniform -> s_load
    float wv[27];
#pragma unroll
    for (int i = 0; i < 27; ++i) wv[i] = wp[i];
    const float bias = a.b[z][m];

    const int xg = tid % 7, y = tid / 7;
    const int x0 = xg*4;
    const unsigned short* ip = a.in[z] + (size_t)nm*LL;
    unsigned short* op = a.out[z] + (size_t)nm*LL;

    Row6 win[3][3];
    // plane t0-1 -> slot 0, plane t0 -> slot 1
#pragma unroll
    for (int dy = 0; dy < 3; ++dy) {
        win[0][dy] = load_row(ip, t0-1, y+dy-1, x0);
        win[1][dy] = load_row(ip, t0,   y+dy-1, x0);
    }
#pragma unroll
    for (int tt = 0; tt < 8; ++tt) {
        const int p0 = tt % 3, p1 = (tt+1) % 3, p2 = (tt+2) % 3;
        const int znew = t0 + tt + 1;
        win[p2][0] = load_row(ip, znew, y-1, x0);
        win[p2][1] = load_row(ip, znew, y,   x0);
        win[p2][2] = load_row(ip, znew, y+1, x0);

        float a0 = bias, a1 = bias, a2 = bias, a3 = bias;
        acc9(a0, a1, a2, a3, win[p0], wv);
        acc9(a0, a1, a2, a3, win[p1], wv + 9);
        acc9(a0, a1, a2, a3, win[p2], wv + 18);

        u16x4 o4 = { f2b(a0), f2b(a1), f2b(a2), f2b(a3) };
        *reinterpret_cast<u16x4*>(op + (size_t)(t0+tt)*(HH*WW) + y*WW + x0) = o4;
    }
}

// ---- d bf16 [set][n][32][L] -> dtf bf16 frag-major --------------------------
__global__ __launch_bounds__(256) void dt_transp(const unsigned short* __restrict__ d,
                                                 short* __restrict__ dtf)
{
    const int set = blockIdx.z, n = blockIdx.y;
    const int t = threadIdx.x;
    const int tau = blockIdx.x*4 + (t >> 6);
    const int L = t & 63;
    const int l = 16*tau + (L & 15);
    const int c0 = 8*(L >> 4);
    const unsigned short* ip = d + ((size_t)set*NB + n)*MIDC*LL + (size_t)c0*LL + l;
    bf16x8 vv;
#pragma unroll
    for (int j = 0; j < 8; ++j) vv[j] = (short)ip[(size_t)j*LL];
    *reinterpret_cast<bf16x8*>(dtf + ((size_t)set*NB + n)*DTF_N_STRIDE +
                               (size_t)tau*512 + L*8) = vv;
}

// ---- pw2 MFMA: [OC x 32] @ [32 x L] + b -> K/Q/V bf16 [n][OC][L] ------------
__global__ __launch_bounds__(256) void pw2_mfma(Pw2M a)
{
    const int z = blockIdx.z, n = blockIdx.y, bx = blockIdx.x;
    int set, chunk;
    if (z < 2)      { set = 0; chunk = z; }
    else if (z < 4) { set = 1; chunk = z - 2; }
    else            { set = 2; chunk = z - 4; }
    const int OC   = (set == 2) ? 256 : 128;
    const int off2 = (set == 0) ? 0 : (set == 1) ? 8 : 16;

    const int t = threadIdx.x, wid = t >> 6, lane = t & 63;
    const int mtile = chunk*4 + wid;
    bf16x8 afr = *reinterpret_cast<const bf16x8*>(
        a.w2f + ((size_t)(off2 + mtile)*512 + lane*8));
    const short* db = a.dtf + ((size_t)set*NB + n)*DTF_N_STRIDE;

    f32x4 acc[4];
#pragma unroll
    for (int i = 0; i < 4; ++i) {
#pragma unroll
        for (int r = 0; r < 4; ++r) acc[i][r] = 0.f;
        bf16x8 bfr = *reinterpret_cast<const bf16x8*>(db + (size_t)(bx*4 + i)*512 + lane*8);
        acc[i] = __builtin_amdgcn_mfma_f32_16x16x32_bf16(afr, bfr, acc[i], 0, 0, 0);
    }
    const float* bb = a.b[set];
    unsigned short* op = a.out[set] + (size_t)n*OC*LL;
    const int col = lane & 15;
    const int m0 = 16*mtile + (lane >> 4)*4;
#pragma unroll
    for (int r = 0; r < 4; ++r) {
        const float bv = bb[m0 + r];
#pragma unroll
        for (int i = 0; i < 4; ++i)
            op[(size_t)(m0 + r)*LL + (bx*4 + i)*16 + col] = f2b(acc[i][r] + bv);
    }
}

// ---- context partials over 49 L-tiles (bf16 in), + per-row exp-sums ---------
__global__ __launch_bounds__(256) void ctx_partial(
    const unsigned short* __restrict__ Kb, const unsigned short* __restrict__ Vb,
    float* __restrict__ ctxp)
{
    const int nh = blockIdx.y;
    const int sp = blockIdx.x;
    const int n = nh >> 3, h = nh & 7;
    __shared__ float Kt[HK][260];
    __shared__ float Vt[HV][260];
    const int t = threadIdx.x;
    const int l0 = sp*256;
    const unsigned short* Kp = Kb + ((size_t)(n*KCC + h*HK))*LL + l0;
    const unsigned short* Vp = Vb + ((size_t)(n*VCC + h*HV))*LL + l0;
#pragma unroll
    for (int m = 0; m < HK; ++m) Kt[m][t] = __expf(b2f(Kp[(size_t)m*LL + t]));
#pragma unroll
    for (int m = 0; m < HV; ++m) Vt[m][t] = b2f(Vp[(size_t)m*LL + t]);
    __syncthreads();

    const int kk = t >> 4, v0 = t & 15;
    float acc0 = 0.f, acc1 = 0.f, asum = 0.f;
#pragma unroll 2
    for (int j = 0; j < 256; j += 4) {
        float4 kv = *reinterpret_cast<const float4*>(&Kt[kk][j]);
        float4 va = *reinterpret_cast<const float4*>(&Vt[v0][j]);
        float4 vb = *reinterpret_cast<const float4*>(&Vt[v0+16][j]);
        acc0 += kv.x*va.x; acc0 += kv.y*va.y; acc0 += kv.z*va.z; acc0 += kv.w*va.w;
        acc1 += kv.x*vb.x; acc1 += kv.y*vb.y; acc1 += kv.z*vb.z; acc1 += kv.w*vb.w;
        asum += kv.x + kv.y + kv.z + kv.w;
    }
    float* cp = ctxp + ((size_t)nh*CTXSPLIT + sp)*CTXSTR;
    cp[kk*HV + v0]      = acc0;
    cp[kk*HV + v0 + 16] = acc1;
    if (v0 == 0) cp[512 + kk] = asum;
}

__global__ void ctx_reduce(const float* __restrict__ ctxp, float* __restrict__ ctx)
{
    const int idx = blockIdx.x*256 + threadIdx.x;   // 16384
    const int nh = idx >> 9;
    const int p  = idx & 511;
    const int k  = p >> 5;
    float s = 0.f, se = 0.f;
    for (int sp = 0; sp < CTXSPLIT; ++sp) {
        const float* cp = ctxp + ((size_t)nh*CTXSPLIT + sp)*CTXSTR;
        s  += cp[p];
        se += cp[512 + k];
    }
    ctx[idx] = s / se;
}

// ---- attended (fused Q-softmax), emits agg in pw1 frag layout ---------------
__global__ __launch_bounds__(256) void attended_kernel(
    const float* __restrict__ ctx, const unsigned short* __restrict__ Qb,
    short* __restrict__ aggf)
{
    const int nh = blockIdx.y;
    const int n = nh >> 3, h = nh & 7;
    const int l = blockIdx.x*256 + threadIdx.x;
    const float* __restrict__ cl = ctx + (size_t)nh*512;

    const unsigned short* Qp = Qb + ((size_t)(n*KCC + h*HK))*LL + l;
    float q[HK];
    float mx = -1e30f;
#pragma unroll
    for (int k = 0; k < HK; ++k) { q[k] = b2f(Qp[(size_t)k*LL]); mx = fmaxf(mx, q[k]); }
    float s = 0.f;
#pragma unroll
    for (int k = 0; k < HK; ++k) { q[k] = __expf(q[k] - mx); s += q[k]; }
    const float inv = 1.f / s;
#pragma unroll
    for (int k = 0; k < HK; ++k) q[k] *= inv;

    float av[HV];
#pragma unroll 4
    for (int v = 0; v < HV; ++v) {
        float acc = 0.f;
#pragma unroll
        for (int k = 0; k < HK; ++k) acc += q[k] * cl[k*HV + v];
        av[v] = acc;
    }
    short* ob = aggf + (size_t)n*XTF_N_STRIDE + ((size_t)((l >> 4)*8 + h))*512;
#pragma unroll
    for (int qd = 0; qd < 4; ++qd) {
        bf16x8 vv;
#pragma unroll
        for (int j = 0; j < 8; ++j) vv[j] = (short)f2b(av[qd*8 + j]);
        *reinterpret_cast<bf16x8*>(ob + (qd*16 + (l & 15))*8) = vv;
    }
}

// ---- pw2r MFMA: reproj + residual + LN partials -----------------------------
__global__ __launch_bounds__(256) void pw2r_mfma(
    const short* __restrict__ dtf, const short* __restrict__ w2f,
    const float* __restrict__ bias, const float* __restrict__ resid,
    float* __restrict__ xout, float* __restrict__ part)
{
    const int z = blockIdx.z, n = blockIdx.y, bx = blockIdx.x;
    const int t = threadIdx.x, wid = t >> 6, lane = t & 63;
    const int mtile = z*4 + wid;
    bf16x8 afr = *reinterpret_cast<const bf16x8*>(
        w2f + ((size_t)(32 + mtile)*512 + lane*8));
    const short* db = dtf + (size_t)n*DTF_N_STRIDE;

    f32x4 acc[4];
#pragma unroll
    for (int i = 0; i < 4; ++i) {
#pragma unroll
        for (int r = 0; r < 4; ++r) acc[i][r] = 0.f;
        bf16x8 bfr = *reinterpret_cast<const bf16x8*>(db + (size_t)(bx*4 + i)*512 + lane*8);
        acc[i] = __builtin_amdgcn_mfma_f32_16x16x32_bf16(afr, bfr, acc[i], 0, 0, 0);
    }
    const int col = lane & 15;
    const int m0 = 16*mtile + (lane >> 4)*4;
    float s1 = 0.f, s2 = 0.f;
#pragma unroll
    for (int r = 0; r < 4; ++r) {
        const float bv = bias[m0 + r];
#pragma unroll
        for (int i = 0; i < 4; ++i) {
            const size_t off = (size_t)(n*CIN + m0 + r)*LL + (bx*4 + i)*16 + col;
            const float v = acc[i][r] + bv + resid[off];
            xout[off] = v;
            s1 += v; s2 += v*v;
        }
    }
    __shared__ float red[256];
    const int bid = (z*NB + n)*196 + bx;          // < 3136
    red[t] = s1; __syncthreads();
    for (int s = 128; s > 0; s >>= 1) { if (t < s) red[t] += red[t+s]; __syncthreads(); }
    if (t == 0) part[2*bid] = red[0];
    __syncthreads();
    red[t] = s2; __syncthreads();
    for (int s = 128; s > 0; s >>= 1) { if (t < s) red[t] += red[t+s]; __syncthreads(); }
    if (t == 0) part[2*bid + 1] = red[0];
}

__global__ void stats_kernel(const float* __restrict__ part, int nblocks,
                             float* __restrict__ stats)
{
    __shared__ float r1[256], r2[256];
    const int t = threadIdx.x;
    float s1 = 0.f, s2 = 0.f;
    for (int i = t; i < nblocks; i += 256) { s1 += part[2*i]; s2 += part[2*i+1]; }
    r1[t] = s1; r2[t] = s2; __syncthreads();
    for (int s = 128; s > 0; s >>= 1) { if (t < s) { r1[t] += r1[t+s]; r2[t] += r2[t+s]; } __syncthreads(); }
    if (t == 0) {
        const float M = (float)NB*CIN*LL;
        const float mu = r1[0]/M;
        const float var = r2[0]/M - mu*mu;
        stats[0] = mu;
        stats[1] = 1.0f/sqrtf(var + EPSV);
    }
}

__global__ __launch_bounds__(256) void norm_kernel(
    const float* __restrict__ x, const float* __restrict__ stats,
    float* __restrict__ out)
{
    const float mu = stats[0], inv = stats[1];
    const size_t total = (size_t)NB*CIN*LL;
    for (size_t i = ((size_t)blockIdx.x*256 + threadIdx.x)*4; i < total;
         i += (size_t)gridDim.x*256*4) {
        float4 v = *reinterpret_cast<const float4*>(x + i);
        float4 o;
        o.x = (v.x-mu)*inv; o.y = (v.y-mu)*inv; o.z = (v.z-mu)*inv; o.w = (v.w-mu)*inv;
        *reinterpret_cast<float4*>(out + i) = o;
    }
}

// ------------------------------- launcher ------------------------------------
extern "C" void kernel_launch(void* const* d_in, const int* in_sizes, int n_in,
                              void* d_out, int out_size, void* d_ws, size_t ws_size,
                              hipStream_t stream) {
    const float* input   = (const float*)d_in[0];
    const float* k_pw1_w = (const float*)d_in[1];
    const float* k_pw1_b = (const float*)d_in[2];
    const float* k_dw_w  = (const float*)d_in[3];
    const float* k_dw_b  = (const float*)d_in[4];
    const float* k_pw2_w = (const float*)d_in[5];
    const float* k_pw2_b = (const float*)d_in[6];
    const float* q_pw1_w = (const float*)d_in[7];
    const float* q_pw1_b = (const float*)d_in[8];
    const float* q_dw_w  = (const float*)d_in[9];
    const float* q_dw_b  = (const float*)d_in[10];
    const float* q_pw2_w = (const float*)d_in[11];
    const float* q_pw2_b = (const float*)d_in[12];
    const float* v_pw1_w = (const float*)d_in[13];
    const float* v_pw1_b = (const float*)d_in[14];
    const float* v_dw_w  = (const float*)d_in[15];
    const float* v_dw_b  = (const float*)d_in[16];
    const float* v_pw2_w = (const float*)d_in[17];
    const float* v_pw2_b = (const float*)d_in[18];
    const float* r_pw1_w = (const float*)d_in[19];
    const float* r_pw1_b = (const float*)d_in[20];
    const float* r_dw_w  = (const float*)d_in[21];
    const float* r_dw_b  = (const float*)d_in[22];
    const float* r_pw2_w = (const float*)d_in[23];
    const float* r_pw2_b = (const float*)d_in[24];

    // ---- workspace carve (bytes) ----
    char* base = (char*)d_ws;
    // R0: xtf -> dbuf(kqv bf16) -> aggf (sequential tenants)
    short* xtf  = (short*)base;
    unsigned short* dbuf = (unsigned short*)base;
    short* aggf = (short*)base;
    // R1: mid(kqv bf16) -> {mid_r, d_r, dtf_r}
    unsigned short* midb  = (unsigned short*)(base + 25690112);
    unsigned short* mid_r = midb;
    unsigned short* d_r   = (unsigned short*)(base + 25690112 + 6422528);
    short* dtf_r          = (short*)(base + 25690112 + 12845056);
    // R2: dtf (kqv)
    short* dtf = (short*)(base + 44957696);
    // R3: K,Q,V bf16 -> x fp32
    unsigned short* Kb = (unsigned short*)(base + 54591488);
    unsigned short* Qb = (unsigned short*)(base + 67436544);
    unsigned short* Vb = (unsigned short*)(base + 80281600);
    float* xb = (float*)(base + 54591488);
    // R4 (small)
    char* H = base + 105971712;
    float* ctxp   = (float*)H;                    // 3,411,968 B
    float* ctx    = (float*)(H + 3411968);
    float* part   = (float*)(H + 3477504);
    float* statsp = (float*)(H + 3502592);
    short* w1f    = (short*)(H + 3502656);
    short* w2f    = (short*)(H + 3568192);

    // 1. weight fragment tables
    {
        WconvA a;
        a.w1[0]=k_pw1_w; a.w1[1]=q_pw1_w; a.w1[2]=v_pw1_w; a.w1[3]=r_pw1_w;
        a.w2[0]=k_pw2_w; a.w2[1]=q_pw2_w; a.w2[2]=v_pw2_w; a.w2[3]=r_pw2_w;
        wconv_kernel<<<28, 256, 0, stream>>>(a, w1f, w2f);
    }
    // 2. input -> frag-major bf16
    transp_in<<<dim3(1568, NB), 256, 0, stream>>>(input, xtf);
    // 3. pw1 k/q/v (MFMA, shared B) -> mid bf16
    {
        Pw1M a;
        a.wt[0]=w1f;        a.wt[1]=w1f+8192;   a.wt[2]=w1f+16384;
        a.b[0]=k_pw1_b;     a.b[1]=q_pw1_b;     a.b[2]=v_pw1_b;
        a.out[0]=midb;      a.out[1]=midb+MID_SET_STRIDE; a.out[2]=midb+2*MID_SET_STRIDE;
        pw1_mfma_t<3><<<dim3(98, NB), 256, 0, stream>>>(xtf, a);
    }
    // 4. depthwise k/q/v (register sliding window) -> dbuf bf16
    {
        DwA a;
        a.in[0]=midb; a.in[1]=midb+MID_SET_STRIDE; a.in[2]=midb+2*MID_SET_STRIDE;
        a.w[0]=k_dw_w; a.w[1]=q_dw_w; a.w[2]=v_dw_w;
        a.b[0]=k_dw_b; a.b[1]=q_dw_b; a.b[2]=v_dw_b;
        a.out[0]=dbuf; a.out[1]=dbuf+MID_SET_STRIDE; a.out[2]=dbuf+2*MID_SET_STRIDE;
        dw_reg<<<dim3(2, NB*MIDC, 3), 256, 0, stream>>>(a);
    }
    // 5. d -> frag-major bf16
    dt_transp<<<dim3(196, NB, 3), 256, 0, stream>>>(dbuf, dtf);
    // 6. pw2 k/q/v (MFMA) -> K,Q,V bf16
    {
        Pw2M a;
        a.w2f = w2f; a.dtf = dtf;
        a.b[0]=k_pw2_b; a.b[1]=q_pw2_b; a.b[2]=v_pw2_b;
        a.out[0]=Kb; a.out[1]=Qb; a.out[2]=Vb;
        pw2_mfma<<<dim3(196, NB, 8), 256, 0, stream>>>(a);
    }
    // 7-8. context
    ctx_partial<<<dim3(CTXSPLIT, NB*HC), 256, 0, stream>>>(Kb, Vb, ctxp);
    ctx_reduce<<<64, 256, 0, stream>>>(ctxp, ctx);
    // 9. attended -> aggf (frag layout)
    attended_kernel<<<dim3(49, NB*HC), 256, 0, stream>>>(ctx, Qb, aggf);
    // 10. pw1 r (MFMA) -> mid_r bf16
    {
        Pw1M a;
        a.wt[0]=w1f+24576; a.wt[1]=a.wt[0]; a.wt[2]=a.wt[0];
        a.b[0]=r_pw1_b;    a.b[1]=a.b[0];   a.b[2]=a.b[0];
        a.out[0]=mid_r;    a.out[1]=a.out[0]; a.out[2]=a.out[0];
        pw1_mfma_t<1><<<dim3(98, NB), 256, 0, stream>>>(aggf, a);
    }
    // 11. depthwise r -> d_r bf16
    {
        DwA a;
        a.in[0]=mid_r; a.w[0]=r_dw_w; a.b[0]=r_dw_b; a.out[0]=d_r;
        a.in[1]=a.in[0]; a.w[1]=a.w[0]; a.b[1]=a.b[0]; a.out[1]=a.out[0];
        a.in[2]=a.in[0]; a.w[2]=a.w[0]; a.b[2]=a.b[0]; a.out[2]=a.out[0];
        dw_reg<<<dim3(2, NB*MIDC, 1), 256, 0, stream>>>(a);
    }
    // 12. d_r -> frag
    dt_transp<<<dim3(196, NB, 1), 256, 0, stream>>>(d_r, dtf_r);
    // 13. pw2 r + residual + LN partials -> x fp32
    pw2r_mfma<<<dim3(196, NB, 4), 256, 0, stream>>>(dtf_r, w2f, r_pw2_b, input, xb, part);
    // 14-15. global layernorm
    stats_kernel<<<1, 256, 0, stream>>>(part, 3136, statsp);
    norm_kernel<<<2048, 256, 0, stream>>>(xb, statsp, (float*)d_out);
}

// Round 8
// 185.860 us; speedup vs baseline: 2.2693x; 1.0068x over previous
//
#include <hip/hip_runtime.h>
#include <cstddef>

// Problem constants
#define NB   4
#define CIN  256
#define TT   16
#define HH   28
#define WW   28
#define LL   12544           // 16*28*28 = 784*16
#define MIDC 32
#define KCC  128
#define VCC  256
#define HC   8
#define HK   16
#define HV   32
#define CTXSPLIT 49
#define CTXSTR 544
#define EPSV 1e-5f

typedef __attribute__((ext_vector_type(8))) short bf16x8;
typedef __attribute__((ext_vector_type(4))) float f32x4;
typedef __attribute__((ext_vector_type(4))) unsigned short u16x4;

__device__ __forceinline__ float b2f(unsigned short u) {
    return __builtin_bit_cast(float, ((unsigned int)u) << 16);
}
__device__ __forceinline__ unsigned short f2b(float f) {
    unsigned int u = __builtin_bit_cast(unsigned int, f);
    u += 0x7FFFu + ((u >> 16) & 1u);          // RNE
    return (unsigned short)(u >> 16);
}

// sizes (elements)
#define XTF_N_STRIDE 3211264ull        // 784*8*512 shorts per sample
#define DTF_N_STRIDE 401408ull         // 784*512 shorts per sample (per set)
#define MID_SET_STRIDE 1605632ull      // 4*32*12544 elems per set

struct WconvA { const float* w1[4]; const float* w2[4]; };
struct Pw1M  { const short* wt[3]; const float* b[3]; unsigned short* out[3]; };
struct DwA   { const unsigned short* in[3]; const float* w[3]; const float* b[3]; unsigned short* out[3]; };
struct Pw2M  { const short* w2f; const short* dtf; const float* b[3]; unsigned short* out[3]; };

// ---- weights -> fragment-major bf16 tables --------------------------------
__global__ __launch_bounds__(256) void wconv_kernel(WconvA a, short* __restrict__ w1f,
                                                    short* __restrict__ w2f)
{
    const int g = blockIdx.x*256 + threadIdx.x;
    if (g < 4096) {
        const int L = g & 63, kap = (g >> 6) & 7, mt = (g >> 9) & 1, set = g >> 10;
        const int m = 16*mt + (L & 15);
        const int c0 = 32*kap + 8*(L >> 4);
        const float* wp = a.w1[set] + m*CIN + c0;
#pragma unroll
        for (int j = 0; j < 8; ++j) w1f[(size_t)g*8 + j] = (short)f2b(wp[j]);
    } else if (g < 4096 + 3072) {
        const int g2 = g - 4096;
        const int L = g2 & 63, mtg = g2 >> 6;
        int set, mtl;
        if (mtg < 8)       { set = 0; mtl = mtg; }
        else if (mtg < 16) { set = 1; mtl = mtg - 8; }
        else if (mtg < 32) { set = 2; mtl = mtg - 16; }
        else               { set = 3; mtl = mtg - 32; }
        const int m = 16*mtl + (L & 15);
        const int c0 = 8*(L >> 4);
        const float* wp = a.w2[set] + m*MIDC + c0;
#pragma unroll
        for (int j = 0; j < 8; ++j) w2f[(size_t)g2*8 + j] = (short)f2b(wp[j]);
    }
}

// ---- input fp32 [N][256][L] -> xtf bf16 frag-major -------------------------
__global__ __launch_bounds__(256) void transp_in(const float* __restrict__ in,
                                                 short* __restrict__ xtf)
{
    const int n = blockIdx.y;
    const int tau = blockIdx.x >> 1;
    const int idx = (blockIdx.x & 1)*256 + threadIdx.x;    // 0..511
    const int kap = idx >> 6, L = idx & 63;
    const int l = 16*tau + (L & 15);
    const int c0 = 32*kap + 8*(L >> 4);
    const float* ip = in + ((size_t)n*CIN + c0)*LL + l;
    bf16x8 vv;
#pragma unroll
    for (int j = 0; j < 8; ++j) vv[j] = (short)f2b(ip[(size_t)j*LL]);
    *reinterpret_cast<bf16x8*>(xtf + (size_t)n*XTF_N_STRIDE +
                               ((size_t)(tau*8 + kap)*512 + L*8)) = vv;
}

// ---- pw1 MFMA (NS sets share B-frags): [32x256]@[256xL] + b -> mid bf16 ----
template<int NS>
__global__ __launch_bounds__(256) void pw1_mfma_t(const short* __restrict__ xtf, Pw1M a)
{
    const int n = blockIdx.y, bx = blockIdx.x;
    const int t = threadIdx.x, wid = t >> 6, lane = t & 63;
    const int mt = wid & 1, lh = wid >> 1;
    const int tau0 = bx*8 + lh*4;
    const short* xb = xtf + (size_t)n*XTF_N_STRIDE;

    f32x4 acc[NS][4];
#pragma unroll
    for (int s = 0; s < NS; ++s)
#pragma unroll
        for (int i = 0; i < 4; ++i)
#pragma unroll
            for (int r = 0; r < 4; ++r) acc[s][i][r] = 0.f;

    for (int kap = 0; kap < 8; ++kap) {
        bf16x8 bfr[4];
#pragma unroll
        for (int i = 0; i < 4; ++i)
            bfr[i] = *reinterpret_cast<const bf16x8*>(
                xb + ((size_t)((tau0 + i)*8 + kap)*512 + lane*8));
#pragma unroll
        for (int s = 0; s < NS; ++s) {
            bf16x8 afr = *reinterpret_cast<const bf16x8*>(
                a.wt[s] + ((mt*8 + kap)*512 + lane*8));
#pragma unroll
            for (int i = 0; i < 4; ++i)
                acc[s][i] = __builtin_amdgcn_mfma_f32_16x16x32_bf16(afr, bfr[i], acc[s][i], 0, 0, 0);
        }
    }
    const int col = lane & 15;
    const int m0 = mt*16 + (lane >> 4)*4;
#pragma unroll
    for (int s = 0; s < NS; ++s) {
        const float* bb = a.b[s];
        unsigned short* op = a.out[s] + (size_t)n*MIDC*LL;
#pragma unroll
        for (int r = 0; r < 4; ++r) {
            const float bv = bb[m0 + r];
#pragma unroll
            for (int i = 0; i < 4; ++i)
                op[(size_t)(m0 + r)*LL + (tau0 + i)*16 + col] = f2b(acc[s][i][r] + bv);
        }
    }
}

// ---- depthwise 3x3x3, pad 1: register sliding window over t ----------------
struct Row6 { float v[6]; };

__device__ __forceinline__ Row6 load_row(const unsigned short* base, int zz, int yy, int x0)
{
    Row6 r;
    const bool ok = (zz >= 0) && (zz < TT) && (yy >= 0) && (yy < HH);
    if (ok) {
        const unsigned short* p = base + zz*(HH*WW) + yy*WW + x0;
        u16x4 m4 = *reinterpret_cast<const u16x4*>(p);
        r.v[0] = (x0 > 0)  ? b2f(p[-1]) : 0.f;
        r.v[1] = b2f(m4[0]); r.v[2] = b2f(m4[1]);
        r.v[3] = b2f(m4[2]); r.v[4] = b2f(m4[3]);
        r.v[5] = (x0 < 24) ? b2f(p[4]) : 0.f;
    } else {
#pragma unroll
        for (int i = 0; i < 6; ++i) r.v[i] = 0.f;
    }
    return r;
}

__device__ __forceinline__ void acc9(float& a0, float& a1, float& a2, float& a3,
                                     const Row6* rows, const float* w9)
{
#pragma unroll
    for (int dy = 0; dy < 3; ++dy)
#pragma unroll
        for (int dx = 0; dx < 3; ++dx) {
            const float wv = w9[dy*3 + dx];
            a0 = fmaf(wv, rows[dy].v[0 + dx], a0);
            a1 = fmaf(wv, rows[dy].v[1 + dx], a1);
            a2 = fmaf(wv, rows[dy].v[2 + dx], a2);
            a3 = fmaf(wv, rows[dy].v[3 + dx], a3);
        }
}

__global__ __launch_bounds__(256) void dw_reg(DwA a)
{
    const int tid = threadIdx.x;
    if (tid >= 196) return;                  // 7 x-groups * 28 y
    const int z  = blockIdx.z;
    const int nm = blockIdx.y;               // n*32 + m
    const int m  = nm & (MIDC-1);
    const int t0 = blockIdx.x * 8;           // t-half

    const float* wp = a.w[z] + m*27;         // uniform -> s_load
    float wv[27];
#pragma unroll
    for (int i = 0; i < 27; ++i) wv[i] = wp[i];
    const float bias = a.b[z][m];

    const int xg = tid % 7, y = tid / 7;
    const int x0 = xg*4;
    const unsigned short* ip = a.in[z] + (size_t)nm*LL;
    unsigned short* op = a.out[z] + (size_t)nm*LL;

    Row6 win[3][3];
    // plane t0-1 -> slot 0, plane t0 -> slot 1
#pragma unroll
    for (int dy = 0; dy < 3; ++dy) {
        win[0][dy] = load_row(ip, t0-1, y+dy-1, x0);
        win[1][dy] = load_row(ip, t0,   y+dy-1, x0);
    }
#pragma unroll
    for (int tt = 0; tt < 8; ++tt) {
        const int p0 = tt % 3, p1 = (tt+1) % 3, p2 = (tt+2) % 3;
        const int znew = t0 + tt + 1;
        win[p2][0] = load_row(ip, znew, y-1, x0);
        win[p2][1] = load_row(ip, znew, y,   x0);
        win[p2][2] = load_row(ip, znew, y+1, x0);

        float a0 = bias, a1 = bias, a2 = bias, a3 = bias;
        acc9(a0, a1, a2, a3, win[p0], wv);
        acc9(a0, a1, a2, a3, win[p1], wv + 9);
        acc9(a0, a1, a2, a3, win[p2], wv + 18);

        u16x4 o4 = { f2b(a0), f2b(a1), f2b(a2), f2b(a3) };
        *reinterpret_cast<u16x4*>(op + (size_t)(t0+tt)*(HH*WW) + y*WW + x0) = o4;
    }
}

// ---- d bf16 [set][n][32][L] -> dtf bf16 frag-major --------------------------
__global__ __launch_bounds__(256) void dt_transp(const unsigned short* __restrict__ d,
                                                 short* __restrict__ dtf)
{
    const int set = blockIdx.z, n = blockIdx.y;
    const int t = threadIdx.x;
    const int tau = blockIdx.x*4 + (t >> 6);
    const int L = t & 63;
    const int l = 16*tau + (L & 15);
    const int c0 = 8*(L >> 4);
    const unsigned short* ip = d + ((size_t)set*NB + n)*MIDC*LL + (size_t)c0*LL + l;
    bf16x8 vv;
#pragma unroll
    for (int j = 0; j < 8; ++j) vv[j] = (short)ip[(size_t)j*LL];
    *reinterpret_cast<bf16x8*>(dtf + ((size_t)set*NB + n)*DTF_N_STRIDE +
                               (size_t)tau*512 + L*8) = vv;
}

// ---- pw2 MFMA: [OC x 32] @ [32 x L] + b -> K/Q/V bf16 [n][OC][L] ------------
__global__ __launch_bounds__(256) void pw2_mfma(Pw2M a)
{
    const int z = blockIdx.z, n = blockIdx.y, bx = blockIdx.x;
    int set, chunk;
    if (z < 2)      { set = 0; chunk = z; }
    else if (z < 4) { set = 1; chunk = z - 2; }
    else            { set = 2; chunk = z - 4; }
    const int OC   = (set == 2) ? 256 : 128;
    const int off2 = (set == 0) ? 0 : (set == 1) ? 8 : 16;

    const int t = threadIdx.x, wid = t >> 6, lane = t & 63;
    const int mtile = chunk*4 + wid;
    bf16x8 afr = *reinterpret_cast<const bf16x8*>(
        a.w2f + ((size_t)(off2 + mtile)*512 + lane*8));
    const short* db = a.dtf + ((size_t)set*NB + n)*DTF_N_STRIDE;

    f32x4 acc[4];
#pragma unroll
    for (int i = 0; i < 4; ++i) {
#pragma unroll
        for (int r = 0; r < 4; ++r) acc[i][r] = 0.f;
        bf16x8 bfr = *reinterpret_cast<const bf16x8*>(db + (size_t)(bx*4 + i)*512 + lane*8);
        acc[i] = __builtin_amdgcn_mfma_f32_16x16x32_bf16(afr, bfr, acc[i], 0, 0, 0);
    }
    const float* bb = a.b[set];
    unsigned short* op = a.out[set] + (size_t)n*OC*LL;
    const int col = lane & 15;
    const int m0 = 16*mtile + (lane >> 4)*4;
#pragma unroll
    for (int r = 0; r < 4; ++r) {
        const float bv = bb[m0 + r];
#pragma unroll
        for (int i = 0; i < 4; ++i)
            op[(size_t)(m0 + r)*LL + (bx*4 + i)*16 + col] = f2b(acc[i][r] + bv);
    }
}

// ---- context partials over 49 L-tiles (bf16 in), + per-row exp-sums ---------
__global__ __launch_bounds__(256) void ctx_partial(
    const unsigned short* __restrict__ Kb, const unsigned short* __restrict__ Vb,
    float* __restrict__ ctxp)
{
    const int nh = blockIdx.y;
    const int sp = blockIdx.x;
    const int n = nh >> 3, h = nh & 7;
    __shared__ float Kt[HK][260];
    __shared__ float Vt[HV][260];
    const int t = threadIdx.x;
    const int l0 = sp*256;
    const unsigned short* Kp = Kb + ((size_t)(n*KCC + h*HK))*LL + l0;
    const unsigned short* Vp = Vb + ((size_t)(n*VCC + h*HV))*LL + l0;
#pragma unroll
    for (int m = 0; m < HK; ++m) Kt[m][t] = __expf(b2f(Kp[(size_t)m*LL + t]));
#pragma unroll
    for (int m = 0; m < HV; ++m) Vt[m][t] = b2f(Vp[(size_t)m*LL + t]);
    __syncthreads();

    const int kk = t >> 4, v0 = t & 15;
    float acc0 = 0.f, acc1 = 0.f, asum = 0.f;
#pragma unroll 2
    for (int j = 0; j < 256; j += 4) {
        float4 kv = *reinterpret_cast<const float4*>(&Kt[kk][j]);
        float4 va = *reinterpret_cast<const float4*>(&Vt[v0][j]);
        float4 vb = *reinterpret_cast<const float4*>(&Vt[v0+16][j]);
        acc0 += kv.x*va.x; acc0 += kv.y*va.y; acc0 += kv.z*va.z; acc0 += kv.w*va.w;
        acc1 += kv.x*vb.x; acc1 += kv.y*vb.y; acc1 += kv.z*vb.z; acc1 += kv.w*vb.w;
        asum += kv.x + kv.y + kv.z + kv.w;
    }
    float* cp = ctxp + ((size_t)nh*CTXSPLIT + sp)*CTXSTR;
    cp[kk*HV + v0]      = acc0;
    cp[kk*HV + v0 + 16] = acc1;
    if (v0 == 0) cp[512 + kk] = asum;
}

__global__ void ctx_reduce(const float* __restrict__ ctxp, float* __restrict__ ctx)
{
    const int idx = blockIdx.x*256 + threadIdx.x;   // 16384
    const int nh = idx >> 9;
    const int p  = idx & 511;
    const int k  = p >> 5;
    float s = 0.f, se = 0.f;
    for (int sp = 0; sp < CTXSPLIT; ++sp) {
        const float* cp = ctxp + ((size_t)nh*CTXSPLIT + sp)*CTXSTR;
        s  += cp[p];
        se += cp[512 + k];
    }
    ctx[idx] = s / se;
}

// ---- attended (fused Q-softmax), emits agg in pw1 frag layout ---------------
__global__ __launch_bounds__(256) void attended_kernel(
    const float* __restrict__ ctx, const unsigned short* __restrict__ Qb,
    short* __restrict__ aggf)
{
    const int nh = blockIdx.y;
    const int n = nh >> 3, h = nh & 7;
    const int l = blockIdx.x*256 + threadIdx.x;
    const float* __restrict__ cl = ctx + (size_t)nh*512;

    const unsigned short* Qp = Qb + ((size_t)(n*KCC + h*HK))*LL + l;
    float q[HK];
    float mx = -1e30f;
#pragma unroll
    for (int k = 0; k < HK; ++k) { q[k] = b2f(Qp[(size_t)k*LL]); mx = fmaxf(mx, q[k]); }
    float s = 0.f;
#pragma unroll
    for (int k = 0; k < HK; ++k) { q[k] = __expf(q[k] - mx); s += q[k]; }
    const float inv = 1.f / s;
#pragma unroll
    for (int k = 0; k < HK; ++k) q[k] *= inv;

    float av[HV];
#pragma unroll 4
    for (int v = 0; v < HV; ++v) {
        float acc = 0.f;
#pragma unroll
        for (int k = 0; k < HK; ++k) acc += q[k] * cl[k*HV + v];
        av[v] = acc;
    }
    short* ob = aggf + (size_t)n*XTF_N_STRIDE + ((size_t)((l >> 4)*8 + h))*512;
#pragma unroll
    for (int qd = 0; qd < 4; ++qd) {
        bf16x8 vv;
#pragma unroll
        for (int j = 0; j < 8; ++j) vv[j] = (short)f2b(av[qd*8 + j]);
        *reinterpret_cast<bf16x8*>(ob + (qd*16 + (l & 15))*8) = vv;
    }
}

// ---- pw2r MFMA: reproj + residual + LN partials -----------------------------
__global__ __launch_bounds__(256) void pw2r_mfma(
    const short* __restrict__ dtf, const short* __restrict__ w2f,
    const float* __restrict__ bias, const float* __restrict__ resid,
    float* __restrict__ xout, float* __restrict__ part)
{
    const int z = blockIdx.z, n = blockIdx.y, bx = blockIdx.x;
    const int t = threadIdx.x, wid = t >> 6, lane = t & 63;
    const int mtile = z*4 + wid;
    bf16x8 afr = *reinterpret_cast<const bf16x8*>(
        w2f + ((size_t)(32 + mtile)*512 + lane*8));
    const short* db = dtf + (size_t)n*DTF_N_STRIDE;

    f32x4 acc[4];
#pragma unroll
    for (int i = 0; i < 4; ++i) {
#pragma unroll
        for (int r = 0; r < 4; ++r) acc[i][r] = 0.f;
        bf16x8 bfr = *reinterpret_cast<const bf16x8*>(db + (size_t)(bx*4 + i)*512 + lane*8);
        acc[i] = __builtin_amdgcn_mfma_f32_16x16x32_bf16(afr, bfr, acc[i], 0, 0, 0);
    }
    const int col = lane & 15;
    const int m0 = 16*mtile + (lane >> 4)*4;
    float s1 = 0.f, s2 = 0.f;
#pragma unroll
    for (int r = 0; r < 4; ++r) {
        const float bv = bias[m0 + r];
#pragma unroll
        for (int i = 0; i < 4; ++i) {
            const size_t off = (size_t)(n*CIN + m0 + r)*LL + (bx*4 + i)*16 + col;
            const float v = acc[i][r] + bv + resid[off];
            xout[off] = v;
            s1 += v; s2 += v*v;
        }
    }
    __shared__ float red[256];
    const int bid = (z*NB + n)*196 + bx;          // < 3136
    red[t] = s1; __syncthreads();
    for (int s = 128; s > 0; s >>= 1) { if (t < s) red[t] += red[t+s]; __syncthreads(); }
    if (t == 0) part[2*bid] = red[0];
    __syncthreads();
    red[t] = s2; __syncthreads();
    for (int s = 128; s > 0; s >>= 1) { if (t < s) red[t] += red[t+s]; __syncthreads(); }
    if (t == 0) part[2*bid + 1] = red[0];
}

__global__ void stats_kernel(const float* __restrict__ part, int nblocks,
                             float* __restrict__ stats)
{
    __shared__ float r1[256], r2[256];
    const int t = threadIdx.x;
    float s1 = 0.f, s2 = 0.f;
    for (int i = t; i < nblocks; i += 256) { s1 += part[2*i]; s2 += part[2*i+1]; }
    r1[t] = s1; r2[t] = s2; __syncthreads();
    for (int s = 128; s > 0; s >>= 1) { if (t < s) { r1[t] += r1[t+s]; r2[t] += r2[t+s]; } __syncthreads(); }
    if (t == 0) {
        const float M = (float)NB*CIN*LL;
        const float mu = r1[0]/M;
        const float var = r2[0]/M - mu*mu;
        stats[0] = mu;
        stats[1] = 1.0f/sqrtf(var + EPSV);
    }
}

__global__ __launch_bounds__(256) void norm_kernel(
    const float* __restrict__ x, const float* __restrict__ stats,
    float* __restrict__ out)
{
    const float mu = stats[0], inv = stats[1];
    const size_t total = (size_t)NB*CIN*LL;
    for (size_t i = ((size_t)blockIdx.x*256 + threadIdx.x)*4; i < total;
         i += (size_t)gridDim.x*256*4) {
        float4 v = *reinterpret_cast<const float4*>(x + i);
        float4 o;
        o.x = (v.x-mu)*inv; o.y = (v.y-mu)*inv; o.z = (v.z-mu)*inv; o.w = (v.w-mu)*inv;
        *reinterpret_cast<float4*>(out + i) = o;
    }
}

// ------------------------------- launcher ------------------------------------
extern "C" void kernel_launch(void* const* d_in, const int* in_sizes, int n_in,
                              void* d_out, int out_size, void* d_ws, size_t ws_size,
                              hipStream_t stream) {
    const float* input   = (const float*)d_in[0];
    const float* k_pw1_w = (const float*)d_in[1];
    const float* k_pw1_b = (const float*)d_in[2];
    const float* k_dw_w  = (const float*)d_in[3];
    const float* k_dw_b  = (const float*)d_in[4];
    const float* k_pw2_w = (const float*)d_in[5];
    const float* k_pw2_b = (const float*)d_in[6];
    const float* q_pw1_w = (const float*)d_in[7];
    const float* q_pw1_b = (const float*)d_in[8];
    const float* q_dw_w  = (const float*)d_in[9];
    const float* q_dw_b  = (const float*)d_in[10];
    const float* q_pw2_w = (const float*)d_in[11];
    const float* q_pw2_b = (const float*)d_in[12];
    const float* v_pw1_w = (const float*)d_in[13];
    const float* v_pw1_b = (const float*)d_in[14];
    const float* v_dw_w  = (const float*)d_in[15];
    const float* v_dw_b  = (const float*)d_in[16];
    const float* v_pw2_w = (const float*)d_in[17];
    const float* v_pw2_b = (const float*)d_in[18];
    const float* r_pw1_w = (const float*)d_in[19];
    const float* r_pw1_b = (const float*)d_in[20];
    const float* r_dw_w  = (const float*)d_in[21];
    const float* r_dw_b  = (const float*)d_in[22];
    const float* r_pw2_w = (const float*)d_in[23];
    const float* r_pw2_b = (const float*)d_in[24];

    // ---- workspace carve (bytes) ----
    char* base = (char*)d_ws;
    // R0: xtf -> dbuf(kqv bf16) -> aggf (sequential tenants)
    short* xtf  = (short*)base;
    unsigned short* dbuf = (unsigned short*)base;
    short* aggf = (short*)base;
    // R1: mid(kqv bf16) -> {mid_r, d_r, dtf_r}
    unsigned short* midb  = (unsigned short*)(base + 25690112);
    unsigned short* mid_r = midb;
    unsigned short* d_r   = (unsigned short*)(base + 25690112 + 6422528);
    short* dtf_r          = (short*)(base + 25690112 + 12845056);
    // R2: dtf (kqv)
    short* dtf = (short*)(base + 44957696);
    // R3: K,Q,V bf16 -> x fp32
    unsigned short* Kb = (unsigned short*)(base + 54591488);
    unsigned short* Qb = (unsigned short*)(base + 67436544);
    unsigned short* Vb = (unsigned short*)(base + 80281600);
    float* xb = (float*)(base + 54591488);
    // R4 (small)
    char* H = base + 105971712;
    float* ctxp   = (float*)H;                    // 3,411,968 B
    float* ctx    = (float*)(H + 3411968);
    float* part   = (float*)(H + 3477504);
    float* statsp = (float*)(H + 3502592);
    short* w1f    = (short*)(H + 3502656);
    short* w2f    = (short*)(H + 3568192);

    // 1. weight fragment tables
    {
        WconvA a;
        a.w1[0]=k_pw1_w; a.w1[1]=q_pw1_w; a.w1[2]=v_pw1_w; a.w1[3]=r_pw1_w;
        a.w2[0]=k_pw2_w; a.w2[1]=q_pw2_w; a.w2[2]=v_pw2_w; a.w2[3]=r_pw2_w;
        wconv_kernel<<<28, 256, 0, stream>>>(a, w1f, w2f);
    }
    // 2. input -> frag-major bf16
    transp_in<<<dim3(1568, NB), 256, 0, stream>>>(input, xtf);
    // 3. pw1 k/q/v (MFMA, shared B) -> mid bf16
    {
        Pw1M a;
        a.wt[0]=w1f;        a.wt[1]=w1f+8192;   a.wt[2]=w1f+16384;
        a.b[0]=k_pw1_b;     a.b[1]=q_pw1_b;     a.b[2]=v_pw1_b;
        a.out[0]=midb;      a.out[1]=midb+MID_SET_STRIDE; a.out[2]=midb+2*MID_SET_STRIDE;
        pw1_mfma_t<3><<<dim3(98, NB), 256, 0, stream>>>(xtf, a);
    }
    // 4. depthwise k/q/v (register sliding window) -> dbuf bf16
    {
        DwA a;
        a.in[0]=midb; a.in[1]=midb+MID_SET_STRIDE; a.in[2]=midb+2*MID_SET_STRIDE;
        a.w[0]=k_dw_w; a.w[1]=q_dw_w; a.w[2]=v_dw_w;
        a.b[0]=k_dw_b; a.b[1]=q_dw_b; a.b[2]=v_dw_b;
        a.out[0]=dbuf; a.out[1]=dbuf+MID_SET_STRIDE; a.out[2]=dbuf+2*MID_SET_STRIDE;
        dw_reg<<<dim3(2, NB*MIDC, 3), 256, 0, stream>>>(a);
    }
    // 5. d -> frag-major bf16
    dt_transp<<<dim3(196, NB, 3), 256, 0, stream>>>(dbuf, dtf);
    // 6. pw2 k/q/v (MFMA) -> K,Q,V bf16
    {
        Pw2M a;
        a.w2f = w2f; a.dtf = dtf;
        a.b[0]=k_pw2_b; a.b[1]=q_pw2_b; a.b[2]=v_pw2_b;
        a.out[0]=Kb; a.out[1]=Qb; a.out[2]=Vb;
        pw2_mfma<<<dim3(196, NB, 8), 256, 0, stream>>>(a);
    }
    // 7-8. context
    ctx_partial<<<dim3(CTXSPLIT, NB*HC), 256, 0, stream>>>(Kb, Vb, ctxp);
    ctx_reduce<<<64, 256, 0, stream>>>(ctxp, ctx);
    // 9. attended -> aggf (frag layout)
    attended_kernel<<<dim3(49, NB*HC), 256, 0, stream>>>(ctx, Qb, aggf);
    // 10. pw1 r (MFMA) -> mid_r bf16
    {
        Pw1M a;
        a.wt[0]=w1f+24576; a.wt[1]=a.wt[0]; a.wt[2]=a.wt[0];
        a.b[0]=r_pw1_b;    a.b[1]=a.b[0];   a.b[2]=a.b[0];
        a.out[0]=mid_r;    a.out[1]=a.out[0]; a.out[2]=a.out[0];
        pw1_mfma_t<1><<<dim3(98, NB), 256, 0, stream>>>(aggf, a);
    }
    // 11. depthwise r -> d_r bf16
    {
        DwA a;
        a.in[0]=mid_r; a.w[0]=r_dw_w; a.b[0]=r_dw_b; a.out[0]=d_r;
        a.in[1]=a.in[0]; a.w[1]=a.w[0]; a.b[1]=a.b[0]; a.out[1]=a.out[0];
        a.in[2]=a.in[0]; a.w[2]=a.w[0]; a.b[2]=a.b[0]; a.out[2]=a.out[0];
        dw_reg<<<dim3(2, NB*MIDC, 1), 256, 0, stream>>>(a);
    }
    // 12. d_r -> frag
    dt_transp<<<dim3(196, NB, 1), 256, 0, stream>>>(d_r, dtf_r);
    // 13. pw2 r + residual + LN partials -> x fp32
    pw2r_mfma<<<dim3(196, NB, 4), 256, 0, stream>>>(dtf_r, w2f, r_pw2_b, input, xb, part);
    // 14-15. global layernorm
    stats_kernel<<<1, 256, 0, stream>>>(part, 3136, statsp);
    norm_kernel<<<2048, 256, 0, stream>>>(xb, statsp, (float*)d_out);
}